// Round 10
// baseline (659.347 us; speedup 1.0000x reference)
//
#include <hip/hip_runtime.h>
#include <hip/hip_bf16.h>

#define N_NODES 100000
#define N_EDGES 600000
#define DIM     128
#define N_REL   8
#define N_GRAPH 64
#define N_LAYER 3
#define NR      (N_NODES * N_REL)   // 800000
#define NB1     782                 // ceil(NR / 1024)
#define BMF     32                  // fused layer M-tile (100000 % 32 == 0)

typedef __attribute__((ext_vector_type(8))) short short8;
typedef __attribute__((ext_vector_type(4))) float float4v;
typedef unsigned long long ull;

__device__ __forceinline__ float bflo(unsigned int u) {
    return __builtin_bit_cast(float, u << 16);
}
__device__ __forceinline__ float bfhi(unsigned int u) {
    return __builtin_bit_cast(float, u & 0xffff0000u);
}
__device__ __forceinline__ unsigned short f2bf(float f) {
    unsigned int u = __builtin_bit_cast(unsigned int, f);
    u += 0x7fffu + ((u >> 16) & 1u);          // RNE
    return (unsigned short)(u >> 16);
}
__device__ __forceinline__ unsigned int pack2(float a, float b) {
    return (unsigned int)f2bf(a) | ((unsigned int)f2bf(b) << 16);
}
// XOR-swizzle, 8-B granules, 128-B rows (fp8 tiles): 16 granules/row
__device__ __forceinline__ int gswz8(int row, int g) {
    return row * 16 + (g ^ (row & 15));
}
// XOR-swizzle, 16-B granules, 128-B rows (fp8 B tiles): 8 granules/row
__device__ __forceinline__ int gswzh(int row, int g) {
    return row * 8 + (g ^ (row & 7));
}
// XOR-swizzle, 16-B granules, 256-B rows (bf16 tiles): 16 granules/row
__device__ __forceinline__ int gswz(int row, int g) {
    return row * 16 + (g ^ (row & 15));
}

// ---------------- utility: zero int buffer ----------------
__global__ void k_zero(int* __restrict__ p, int n) {
    int i = blockIdx.x * 256 + threadIdx.x;
    if (i < n) p[i] = 0;
}

// ---------------- counting sort of edges by seg = dst*8 + rel (dst-major) ----------------
__global__ void k_hist(const int* __restrict__ ei, const int* __restrict__ et,
                       int* __restrict__ counts) {
    int e = blockIdx.x * 256 + threadIdx.x;
    if (e < N_EDGES) {
        int seg = ei[N_EDGES + e] * N_REL + et[e];
        atomicAdd(&counts[seg], 1);
    }
}

__global__ __launch_bounds__(256) void k_scan1(const int* __restrict__ cnts,
                                               int* __restrict__ part,
                                               int* __restrict__ bsum) {
    __shared__ int sh[256];
    int t = threadIdx.x;
    int base = blockIdx.x * 1024 + t * 4;
    int v0 = (base + 0 < NR) ? cnts[base + 0] : 0;
    int v1 = (base + 1 < NR) ? cnts[base + 1] : 0;
    int v2 = (base + 2 < NR) ? cnts[base + 2] : 0;
    int v3 = (base + 3 < NR) ? cnts[base + 3] : 0;
    int tot = v0 + v1 + v2 + v3;
    sh[t] = tot;
    __syncthreads();
    for (int off = 1; off < 256; off <<= 1) {
        int x = (t >= off) ? sh[t - off] : 0;
        __syncthreads();
        sh[t] += x;
        __syncthreads();
    }
    int exc = sh[t] - tot;
    if (base + 0 < NR) part[base + 0] = exc;
    if (base + 1 < NR) part[base + 1] = exc + v0;
    if (base + 2 < NR) part[base + 2] = exc + v0 + v1;
    if (base + 3 < NR) part[base + 3] = exc + v0 + v1 + v2;
    if (t == 255) bsum[blockIdx.x] = sh[t];
}

__global__ __launch_bounds__(1024) void k_scan2(int* __restrict__ bsum, int nb) {
    __shared__ int sh[1024];
    int t = threadIdx.x;
    int v = (t < nb) ? bsum[t] : 0;
    sh[t] = v;
    __syncthreads();
    for (int off = 1; off < 1024; off <<= 1) {
        int x = (t >= off) ? sh[t - off] : 0;
        __syncthreads();
        sh[t] += x;
        __syncthreads();
    }
    if (t < nb) bsum[t] = sh[t] - v;   // exclusive block offsets
}

__global__ void k_scan3(const int* __restrict__ part, const int* __restrict__ bsum,
                        int* __restrict__ rowptr, int* __restrict__ cursor) {
    int i = blockIdx.x * 256 + threadIdx.x;
    if (i < NR) {
        int v = part[i] + bsum[i >> 10];
        rowptr[i] = v;
        cursor[i] = v;
    }
    if (i == 0) rowptr[NR] = N_EDGES;
}

__global__ void k_scatter(const int* __restrict__ ei, const int* __restrict__ et,
                          int* __restrict__ cursor, int* __restrict__ srcs) {
    int e = blockIdx.x * 256 + threadIdx.x;
    if (e < N_EDGES) {
        int seg = ei[N_EDGES + e] * N_REL + et[e];
        int p = atomicAdd(&cursor[seg], 1);
        srcs[p] = ei[e];
    }
}

// ---------------- x0 = node_emb[node_type], stored bf16x2 ----------------
__global__ void k_gather(const int* __restrict__ nt, const float* __restrict__ emb,
                         unsigned int* __restrict__ x2) {
    int gid = blockIdx.x * 256 + threadIdx.x;
    if (gid < N_NODES * 64) {
        int n = gid >> 6, c2 = gid & 63;
        const float* row = emb + (size_t)nt[n] * DIM + c2 * 2;
        x2[gid] = pack2(row[0], row[1]);
    }
}

// ---------------- weight prep: bf16 root planes only, [l][n][k] ----------------
__global__ void k_wprepr(const float* __restrict__ rootw, unsigned short* __restrict__ WTr) {
    int gid = blockIdx.x * 256 + threadIdx.x;
    if (gid < N_LAYER * 16384) {
        int l = gid / 16384;
        int idx = gid & 16383;
        int n = idx >> 7, k = idx & 127;
        WTr[gid] = f2bf(rootw[((size_t)l * 128 + k) * 128 + n]);
    }
}

// ---------------- weight prep: fp8 e4m3 rel planes, [l][r][n][kpair] ----------------
__global__ void k_wprep8(const float* __restrict__ relw, unsigned short* __restrict__ W8) {
    int gid = blockIdx.x * 256 + threadIdx.x;      // over L*8*128n*64kpair
    if (gid < N_LAYER * 8 * 8192) {
        int l = gid / (8 * 8192);
        int rem = gid - l * 8 * 8192;
        int r = rem >> 13;
        int idx = rem & 8191;
        int n = idx >> 6, kp = idx & 63;
        const float* base = relw + (((size_t)(l * 8 + r) * 128) * 128) + n;
        float w0 = base[(size_t)(2 * kp) * 128];
        float w1 = base[(size_t)(2 * kp + 1) * 128];
        int pk = __builtin_amdgcn_cvt_pk_fp8_f32(w0, w1, 0, false);
        W8[gid] = (unsigned short)(pk & 0xffff);
    }
}

// ---------------- FUSED RGCN layer: in-LDS aggregation + MFMA ----------------
// Block = 256 threads, 32 nodes. Aggregate means (fp8) for all 8 relations into
// LDS, stage root A (bf16), then MFMA 8 fp8 chunks (double-buffered B) + root.
__global__ __launch_bounds__(256) void k_layer(
    const unsigned int* __restrict__ xin,   // [N][64] bf16x2
    unsigned int* __restrict__ xout,        // [N][64] bf16x2
    const int* __restrict__ rowptr,         // [NR+1], seg = dst*8 + rel
    const int* __restrict__ srcs,           // [E] sorted by seg
    const unsigned short* __restrict__ W8,  // [8][128n][64kp] fp8 pairs (this layer)
    const unsigned short* __restrict__ WTr, // [128n][128k] bf16 root (this layer)
    const float* __restrict__ bias)         // [128]
{
    __shared__ __align__(16) ull   A8[8 * 512];    // 32 KB: chunk c at c*512, gswz8
    __shared__ __align__(16) uint4 Aroot[512];     //  8 KB: gswz (16 granules/row)
    __shared__ __align__(16) uint4 Bbuf[2048];     // 32 KB: 2 fp8 halves / 1 bf16 full
    const int t = threadIdx.x;
    const int wv = t >> 6, lane = t & 63;
    const int quad = lane >> 4, l15 = lane & 15;
    const int q = quad, j = l15;
    const int m0 = blockIdx.x * BMF;
    const uint4* x4 = (const uint4*)xin;

    // ---------- phase 1: aggregation into A8 (no barriers) ----------
    for (int grp = wv; grp < 8; grp += 4) {        // grp = wv and wv+4
        const int nb0 = grp * 4;                   // local rows nb0..nb0+3
        int pr = 0;
        {
            int idx = (m0 + nb0) * 8 + lane;       // <= NR by construction
            if (lane < 33) pr = rowptr[idx];
        }
        const int P0 = __shfl(pr, 0);
        const int Dtot = __shfl(pr, 32) - P0;
        int my_src = 0;
        if (lane < Dtot) my_src = srcs[P0 + lane];

        for (int r = 0; r < 8; ++r) {
            int e0 = __shfl(pr, q * 8 + r);
            int e1 = __shfl(pr, q * 8 + r + 1);
            int cnt = e1 - e0;                     // quarter-uniform
            int m1 = max(cnt, __shfl_xor(cnt, 16));
            int maxc = max(m1, __shfl_xor(m1, 32));
            float a0 = 0.f, a1 = 0.f, a2 = 0.f, a3 = 0.f;
            float a4 = 0.f, a5 = 0.f, a6 = 0.f, a7 = 0.f;
            int k = 0;
            for (; k + 2 <= maxc; k += 2) {
                int ei0 = e0 + k, ei1 = e0 + k + 1;
                int r0 = ei0 - P0, r1 = ei1 - P0;
                int s0 = __shfl(my_src, r0 & 63);
                int s1 = __shfl(my_src, r1 & 63);
                if (r0 >= 64) s0 = srcs[ei0];
                if (r1 >= 64) s1 = srcs[ei1];
                bool v0 = (k < cnt), v1 = (k + 1 < cnt);
                uint4 u0, u1;
                if (v0) u0 = x4[(size_t)s0 * 16 + j];
                if (v1) u1 = x4[(size_t)s1 * 16 + j];
                if (v0) {
                    a0 += bflo(u0.x); a1 += bfhi(u0.x);
                    a2 += bflo(u0.y); a3 += bfhi(u0.y);
                    a4 += bflo(u0.z); a5 += bfhi(u0.z);
                    a6 += bflo(u0.w); a7 += bfhi(u0.w);
                }
                if (v1) {
                    a0 += bflo(u1.x); a1 += bfhi(u1.x);
                    a2 += bflo(u1.y); a3 += bfhi(u1.y);
                    a4 += bflo(u1.z); a5 += bfhi(u1.z);
                    a6 += bflo(u1.w); a7 += bfhi(u1.w);
                }
            }
            if (k < maxc) {
                int ei = e0 + k;
                int ridx = ei - P0;
                int s = __shfl(my_src, ridx & 63);
                if (ridx >= 64) s = srcs[ei];
                if (k < cnt) {
                    uint4 u = x4[(size_t)s * 16 + j];
                    a0 += bflo(u.x); a1 += bfhi(u.x);
                    a2 += bflo(u.y); a3 += bfhi(u.y);
                    a4 += bflo(u.z); a5 += bfhi(u.z);
                    a6 += bflo(u.w); a7 += bfhi(u.w);
                }
            }
            float inv = (cnt > 0) ? 1.0f / (float)cnt : 0.f;
            int u0 = __builtin_amdgcn_cvt_pk_fp8_f32(a0 * inv, a1 * inv, 0, false);
            u0 = __builtin_amdgcn_cvt_pk_fp8_f32(a2 * inv, a3 * inv, u0, true);
            int u1 = __builtin_amdgcn_cvt_pk_fp8_f32(a4 * inv, a5 * inv, 0, false);
            u1 = __builtin_amdgcn_cvt_pk_fp8_f32(a6 * inv, a7 * inv, u1, true);
            ull v = ((ull)(unsigned int)u1 << 32) | (unsigned int)(unsigned int)u0;
            A8[r * 512 + gswz8(nb0 + q, j)] = v;
        }
    }
    // ---------- stage Aroot (bf16 rows of this block) ----------
#pragma unroll
    for (int i = 0; i < 2; ++i) {
        int idx = t + 256 * i;                     // 0..511
        int row = idx >> 4, g = idx & 15;
        Aroot[gswz(row, g)] = x4[(size_t)(m0 + row) * 16 + g];
    }
    // ---------- stage B chunk 0 (half 0) ----------
    {
        const uint4* Wc = (const uint4*)W8;        // chunk 0
#pragma unroll
        for (int i = 0; i < 4; ++i) {
            int idx = t + 256 * i;                 // 0..1023
            Bbuf[gswzh(idx >> 3, idx & 7)] = Wc[idx];
        }
    }
    __syncthreads();

    // ---------- phase 2: MFMA over 8 fp8 chunks (B double-buffered) ----------
    float4v acc[2][2];                             // [row-tile][col-half]
    {
        float b0 = bias[wv * 16 + l15];
        float b1 = bias[(wv + 4) * 16 + l15];
        acc[0][0] = (float4v){b0, b0, b0, b0};
        acc[1][0] = (float4v){b0, b0, b0, b0};
        acc[0][1] = (float4v){b1, b1, b1, b1};
        acc[1][1] = (float4v){b1, b1, b1, b1};
    }
    const ull* Bull = (const ull*)Bbuf;
    for (int c = 0; c < 8; ++c) {
        if (c < 7) {                               // prefetch B(c+1) into other half
            const uint4* Wc = (const uint4*)(W8 + (size_t)(c + 1) * 8192);
            int hb = ((c + 1) & 1) * 1024;
#pragma unroll
            for (int i = 0; i < 4; ++i) {
                int idx = t + 256 * i;
                Bbuf[hb + gswzh(idx >> 3, idx & 7)] = Wc[idx];
            }
        }
        int hb = (c & 1) * 2048;                   // ull offset of current half
#pragma unroll
        for (int kk = 0; kk < 4; ++kk) {
            int g8 = kk * 4 + quad;
            long long a0 = (long long)A8[c * 512 + gswz8(l15, g8)];
            long long a1 = (long long)A8[c * 512 + gswz8(16 + l15, g8)];
            int n0 = wv * 16 + l15, n1 = (wv + 4) * 16 + l15;
            long long b0 = (long long)Bull[hb + gswzh(n0, g8 >> 1) * 2 + (g8 & 1)];
            long long b1 = (long long)Bull[hb + gswzh(n1, g8 >> 1) * 2 + (g8 & 1)];
            acc[0][0] = __builtin_amdgcn_mfma_f32_16x16x32_fp8_fp8(a0, b0, acc[0][0], 0, 0, 0);
            acc[0][1] = __builtin_amdgcn_mfma_f32_16x16x32_fp8_fp8(a0, b1, acc[0][1], 0, 0, 0);
            acc[1][0] = __builtin_amdgcn_mfma_f32_16x16x32_fp8_fp8(a1, b0, acc[1][0], 0, 0, 0);
            acc[1][1] = __builtin_amdgcn_mfma_f32_16x16x32_fp8_fp8(a1, b1, acc[1][1], 0, 0, 0);
        }
        __syncthreads();
    }
    // ---------- root chunk: bf16, full Bbuf ----------
    {
        const uint4* Wc = (const uint4*)WTr;       // 2048 uint4
#pragma unroll
        for (int i = 0; i < 8; ++i) {
            int idx = t + 256 * i;
            Bbuf[gswz(idx >> 4, idx & 15)] = Wc[idx];
        }
    }
    __syncthreads();
    {
        const unsigned short* Abfs = (const unsigned short*)Aroot;
        const unsigned short* Bbfs = (const unsigned short*)Bbuf;
#pragma unroll
        for (int kk = 0; kk < 4; ++kk) {
            int g = kk * 4 + quad;
            short8 a0 = *(const short8*)(Abfs + gswz(l15, g) * 8);
            short8 a1 = *(const short8*)(Abfs + gswz(16 + l15, g) * 8);
            short8 b0 = *(const short8*)(Bbfs + gswz(wv * 16 + l15, g) * 8);
            short8 b1 = *(const short8*)(Bbfs + gswz((wv + 4) * 16 + l15, g) * 8);
            acc[0][0] = __builtin_amdgcn_mfma_f32_16x16x32_bf16(a0, b0, acc[0][0], 0, 0, 0);
            acc[0][1] = __builtin_amdgcn_mfma_f32_16x16x32_bf16(a0, b1, acc[0][1], 0, 0, 0);
            acc[1][0] = __builtin_amdgcn_mfma_f32_16x16x32_bf16(a1, b0, acc[1][0], 0, 0, 0);
            acc[1][1] = __builtin_amdgcn_mfma_f32_16x16x32_bf16(a1, b1, acc[1][1], 0, 0, 0);
        }
    }
    // ---------- epilogue: relu, store bf16 ----------
    unsigned short* outs = (unsigned short*)xout;
#pragma unroll
    for (int rt = 0; rt < 2; ++rt) {
#pragma unroll
        for (int cj = 0; cj < 2; ++cj) {
            int colg = (wv + 4 * cj) * 16 + l15;
#pragma unroll
            for (int i = 0; i < 4; ++i) {
                int row = m0 + rt * 16 + quad * 4 + i;   // always < N (N % 32 == 0)
                float v = acc[rt][cj][i];
                v = v > 0.f ? v : 0.f;
                outs[(size_t)row * 128 + colg] = f2bf(v);
            }
        }
    }
}

// ---------------- global mean pool (batch sorted): 64 nodes per wave ----------------
__global__ __launch_bounds__(256) void k_pool(const unsigned int* __restrict__ x2,
                                              const int* __restrict__ batch,
                                              float* __restrict__ gsum,
                                              int* __restrict__ gcnt) {
    const int wv = threadIdx.x >> 6, lane = threadIdx.x & 63;
    const int n0 = (blockIdx.x * 4 + wv) * 64;
    if (n0 >= N_NODES) return;
    int n1 = n0 + 64;
    if (n1 > N_NODES) n1 = N_NODES;
    const int nb = n1 - n0;
    int bb = batch[n0 + (lane < nb ? lane : nb - 1)];
    float a0 = 0.f, a1 = 0.f;
    int run = 0;
    int cur = __shfl(bb, 0);
    for (int base = 0; base < nb; base += 8) {
        unsigned int u[8];
        int m = nb - base;
#pragma unroll
        for (int qq = 0; qq < 8; ++qq)
            if (qq < m) u[qq] = x2[(size_t)(n0 + base + qq) * 64 + lane];
#pragma unroll
        for (int qq = 0; qq < 8; ++qq) {
            if (qq < m) {
                int b = __shfl(bb, base + qq);
                if (b != cur) {
                    atomicAdd(&gsum[cur * 128 + lane * 2], a0);
                    atomicAdd(&gsum[cur * 128 + lane * 2 + 1], a1);
                    if (lane == 0) atomicAdd(&gcnt[cur], run);
                    a0 = a1 = 0.f;
                    run = 0;
                    cur = b;
                }
                a0 += bflo(u[qq]);
                a1 += bfhi(u[qq]);
                ++run;
            }
        }
    }
    atomicAdd(&gsum[cur * 128 + lane * 2], a0);
    atomicAdd(&gsum[cur * 128 + lane * 2 + 1], a1);
    if (lane == 0) atomicAdd(&gcnt[cur], run);
}

// ---------------- MLP heads (fp32) ----------------
__global__ __launch_bounds__(128) void k_heads(
    const float* __restrict__ gsum, const int* __restrict__ gcnt,
    const float* __restrict__ rw1, const float* __restrict__ rb1,
    const float* __restrict__ rw2, const float* __restrict__ rb2,
    const float* __restrict__ sw1, const float* __restrict__ sb1,
    const float* __restrict__ sw2, const float* __restrict__ sb2,
    float* __restrict__ out) {
    __shared__ float g[128];
    __shared__ float parts[2];
    int b = blockIdx.x, t = threadIdx.x;
    int c = gcnt[b];
    float invc = 1.0f / (float)(c > 0 ? c : 1);
    g[t] = gsum[b * 128 + t] * invc;
    __syncthreads();
    float acc = rb1[t];
    for (int d = 0; d < 128; ++d) acc += g[d] * rw1[d * 128 + t];
    float h = acc > 0.f ? acc : 0.f;
    float p = h * rw2[t];
    for (int o = 32; o > 0; o >>= 1) p += __shfl_down(p, o);
    if ((t & 63) == 0) parts[t >> 6] = p;
    __syncthreads();
    if (t == 0) out[b] = parts[0] + parts[1] + rb2[0];
    __syncthreads();
    acc = sb1[t];
    for (int d = 0; d < 128; ++d) acc += g[d] * sw1[d * 128 + t];
    h = acc > 0.f ? acc : 0.f;
    p = h * sw2[t];
    for (int o = 32; o > 0; o >>= 1) p += __shfl_down(p, o);
    if ((t & 63) == 0) parts[t >> 6] = p;
    __syncthreads();
    if (t == 0) out[64 + b] = parts[0] + parts[1] + sb2[0];
}

extern "C" void kernel_launch(void* const* d_in, const int* in_sizes, int n_in,
                              void* d_out, int out_size, void* d_ws, size_t ws_size,
                              hipStream_t stream) {
    const int*   node_type  = (const int*)d_in[0];
    const int*   edge_index = (const int*)d_in[1];
    const int*   edge_type  = (const int*)d_in[2];
    const int*   batch      = (const int*)d_in[3];
    const float* node_emb   = (const float*)d_in[4];
    const float* rel_w      = (const float*)d_in[5];
    const float* root_w     = (const float*)d_in[6];
    const float* bias       = (const float*)d_in[7];
    const float* rw1        = (const float*)d_in[8];
    const float* rb1        = (const float*)d_in[9];
    const float* rw2        = (const float*)d_in[10];
    const float* rb2        = (const float*)d_in[11];
    const float* sw1        = (const float*)d_in[12];
    const float* sb1        = (const float*)d_in[13];
    const float* sw2        = (const float*)d_in[14];
    const float* sb2        = (const float*)d_in[15];
    float* out = (float*)d_out;

    char* ws = (char*)d_ws;
    size_t off = 0;
    auto alloc = [&](size_t bytes) -> void* {
        void* p = ws + off;
        off += (bytes + 255) & ~(size_t)255;
        return p;
    };
    unsigned int*   xa     = (unsigned int*)alloc((size_t)N_NODES * 64 * 4);
    unsigned int*   xb     = (unsigned int*)alloc((size_t)N_NODES * 64 * 4);
    int*            rowptr = (int*)alloc((size_t)(NR + 1) * 4);
    int*            srcs   = (int*)alloc((size_t)N_EDGES * 4);
    int*            bsum   = (int*)alloc(1024 * 4);
    unsigned short* WTr    = (unsigned short*)alloc((size_t)N_LAYER * 16384 * 2);
    unsigned short* W8     = (unsigned short*)alloc((size_t)N_LAYER * 8 * 8192 * 2);
    float*          gsum   = (float*)alloc((64 * 128 + 64) * 4);
    int*            gcnt   = (int*)(gsum + 64 * 128);
    int*            cursor = (int*)alloc((size_t)NR * 4);
    int*            counts = (int*)alloc((size_t)NR * 4);
    if (off > ws_size) return;   // insufficient workspace — fail visibly

    // edge sort (counting sort by dst*8 + rel)
    k_zero<<<(NR + 255) / 256, 256, 0, stream>>>(counts, NR);
    k_zero<<<(64 * 128 + 64 + 255) / 256, 256, 0, stream>>>((int*)gsum, 64 * 128 + 64);
    k_hist<<<(N_EDGES + 255) / 256, 256, 0, stream>>>(edge_index, edge_type, counts);
    k_scan1<<<NB1, 256, 0, stream>>>(counts, cursor, bsum);
    k_scan2<<<1, 1024, 0, stream>>>(bsum, NB1);
    k_scan3<<<(NR + 255) / 256, 256, 0, stream>>>(cursor, bsum, rowptr, cursor);
    k_scatter<<<(N_EDGES + 255) / 256, 256, 0, stream>>>(edge_index, edge_type, cursor, srcs);

    // x0 gather + weight prep (fp8 rel + bf16 root)
    k_gather<<<(N_NODES * 64 + 255) / 256, 256, 0, stream>>>(node_type, node_emb, xa);
    k_wprepr<<<(N_LAYER * 16384 + 255) / 256, 256, 0, stream>>>(root_w, WTr);
    k_wprep8<<<(N_LAYER * 8 * 8192 + 255) / 256, 256, 0, stream>>>(rel_w, W8);

    // 3 fused RGCN layers
    const int lblocks = N_NODES / BMF;   // 3125, exact
    unsigned int* xcur = xa;
    unsigned int* xnext = xb;
    for (int l = 0; l < N_LAYER; ++l) {
        k_layer<<<lblocks, 256, 0, stream>>>(
            xcur, xnext, rowptr, srcs,
            W8 + (size_t)l * 8 * 8192, WTr + (size_t)l * 16384,
            bias + (size_t)l * 128);
        unsigned int* tmp = xcur; xcur = xnext; xnext = tmp;
    }

    // pool + heads
    k_pool<<<(N_NODES + 255) / 256, 256, 0, stream>>>(xcur, batch, gsum, gcnt);
    k_heads<<<64, 128, 0, stream>>>(gsum, gcnt, rw1, rb1, rw2, rb2,
                                    sw1, sb1, sw2, sb2, out);
}

// Round 11
// 483.242 us; speedup vs baseline: 1.3644x; 1.3644x over previous
//
#include <hip/hip_runtime.h>
#include <hip/hip_bf16.h>

#define N_NODES 100000
#define N_EDGES 600000
#define DIM     128
#define N_REL   8
#define N_GRAPH 64
#define N_LAYER 3
#define NR      (N_NODES * N_REL)   // 800000
#define NB1     782                 // ceil(NR / 1024)

typedef __attribute__((ext_vector_type(8))) short short8;
typedef __attribute__((ext_vector_type(4))) float float4v;
typedef __attribute__((ext_vector_type(2))) float float2v;
typedef unsigned long long ull;

__device__ __forceinline__ float bflo(unsigned int u) {
    return __builtin_bit_cast(float, u << 16);
}
__device__ __forceinline__ float bfhi(unsigned int u) {
    return __builtin_bit_cast(float, u & 0xffff0000u);
}
__device__ __forceinline__ unsigned short f2bf(float f) {
    unsigned int u = __builtin_bit_cast(unsigned int, f);
    u += 0x7fffu + ((u >> 16) & 1u);          // RNE
    return (unsigned short)(u >> 16);
}
__device__ __forceinline__ unsigned int pack2(float a, float b) {
    return (unsigned int)f2bf(a) | ((unsigned int)f2bf(b) << 16);
}
// XOR-swizzle, 8-B granules, 128-B rows (fp8 tiles): 16 granules/row
__device__ __forceinline__ int gswz8(int row, int g) {
    return row * 16 + (g ^ (row & 15));
}
// XOR-swizzle, 16-B granules, 256-B rows (bf16 tiles): 16 granules/row
__device__ __forceinline__ int gswz(int row, int g) {
    return row * 16 + (g ^ (row & 15));
}

// ---------------- utility: zero int buffer ----------------
__global__ void k_zero(int* __restrict__ p, int n) {
    int i = blockIdx.x * 256 + threadIdx.x;
    if (i < n) p[i] = 0;
}

// ---------------- counting sort of edges by seg = dst*8 + rel (dst-major) ----------------
__global__ void k_hist(const int* __restrict__ ei, const int* __restrict__ et,
                       int* __restrict__ counts) {
    int e = blockIdx.x * 256 + threadIdx.x;
    if (e < N_EDGES) {
        int seg = ei[N_EDGES + e] * N_REL + et[e];
        atomicAdd(&counts[seg], 1);
    }
}

__global__ __launch_bounds__(256) void k_scan1(const int* __restrict__ cnts,
                                               int* __restrict__ part,
                                               int* __restrict__ bsum) {
    __shared__ int sh[256];
    int t = threadIdx.x;
    int base = blockIdx.x * 1024 + t * 4;
    int v0 = (base + 0 < NR) ? cnts[base + 0] : 0;
    int v1 = (base + 1 < NR) ? cnts[base + 1] : 0;
    int v2 = (base + 2 < NR) ? cnts[base + 2] : 0;
    int v3 = (base + 3 < NR) ? cnts[base + 3] : 0;
    int tot = v0 + v1 + v2 + v3;
    sh[t] = tot;
    __syncthreads();
    for (int off = 1; off < 256; off <<= 1) {
        int x = (t >= off) ? sh[t - off] : 0;
        __syncthreads();
        sh[t] += x;
        __syncthreads();
    }
    int exc = sh[t] - tot;
    if (base + 0 < NR) part[base + 0] = exc;
    if (base + 1 < NR) part[base + 1] = exc + v0;
    if (base + 2 < NR) part[base + 2] = exc + v0 + v1;
    if (base + 3 < NR) part[base + 3] = exc + v0 + v1 + v2;
    if (t == 255) bsum[blockIdx.x] = sh[t];
}

__global__ __launch_bounds__(1024) void k_scan2(int* __restrict__ bsum, int nb) {
    __shared__ int sh[1024];
    int t = threadIdx.x;
    int v = (t < nb) ? bsum[t] : 0;
    sh[t] = v;
    __syncthreads();
    for (int off = 1; off < 1024; off <<= 1) {
        int x = (t >= off) ? sh[t - off] : 0;
        __syncthreads();
        sh[t] += x;
        __syncthreads();
    }
    if (t < nb) bsum[t] = sh[t] - v;   // exclusive block offsets
}

__global__ void k_scan3(const int* __restrict__ part, const int* __restrict__ bsum,
                        int* __restrict__ rowptr, int* __restrict__ cursor) {
    int i = blockIdx.x * 256 + threadIdx.x;
    if (i < NR) {
        int v = part[i] + bsum[i >> 10];
        rowptr[i] = v;
        cursor[i] = v;
    }
    if (i == 0) rowptr[NR] = N_EDGES;
}

__global__ void k_scatter(const int* __restrict__ ei, const int* __restrict__ et,
                          int* __restrict__ cursor, int* __restrict__ srcs) {
    int e = blockIdx.x * 256 + threadIdx.x;
    if (e < N_EDGES) {
        int seg = ei[N_EDGES + e] * N_REL + et[e];
        int p = atomicAdd(&cursor[seg], 1);
        srcs[p] = ei[e];
    }
}

// ---------------- x0 = node_emb[node_type], stored bf16x2 ----------------
__global__ void k_gather(const int* __restrict__ nt, const float* __restrict__ emb,
                         unsigned int* __restrict__ x2) {
    int gid = blockIdx.x * 256 + threadIdx.x;
    if (gid < N_NODES * 64) {
        int n = gid >> 6, c2 = gid & 63;
        const float* row = emb + (size_t)nt[n] * DIM + c2 * 2;
        x2[gid] = pack2(row[0], row[1]);
    }
}

// ---------------- weight prep: bf16 WT (root uses chunk 8) ----------------
__global__ void k_wprep(const float* __restrict__ relw, const float* __restrict__ rootw,
                        unsigned short* __restrict__ WT) {
    int gid = blockIdx.x * 256 + threadIdx.x;
    if (gid < N_LAYER * 9 * 16384) {
        int l = gid / (9 * 16384);
        int rem = gid - l * 9 * 16384;
        int c = rem >> 14;
        int idx = rem & 16383;
        int n = idx >> 7, k = idx & 127;
        float w = (c < 8) ? relw[(((size_t)l * 8 + c) * 128 + k) * 128 + n]
                          : rootw[((size_t)l * 128 + k) * 128 + n];
        WT[gid] = f2bf(w);
    }
}

// ---------------- weight prep: fp8 e4m3 rel planes, [l][r][n][kpair] ----------------
__global__ void k_wprep8(const float* __restrict__ relw, unsigned short* __restrict__ W8) {
    int gid = blockIdx.x * 256 + threadIdx.x;      // over L*8*128n*64kpair
    if (gid < N_LAYER * 8 * 8192) {
        int l = gid / (8 * 8192);
        int rem = gid - l * 8 * 8192;
        int r = rem >> 13;
        int idx = rem & 8191;
        int n = idx >> 6, kp = idx & 63;
        const float* base = relw + (((size_t)(l * 8 + r) * 128) * 128) + n;
        float w0 = base[(size_t)(2 * kp) * 128];
        float w1 = base[(size_t)(2 * kp + 1) * 128];
        int pk = __builtin_amdgcn_cvt_pk_fp8_f32(w0, w1, 0, false);
        W8[gid] = (unsigned short)(pk & 0xffff);
    }
}

// ---------------- per-dst aggregation: 4 nodes per wave, fp8 out, pk-f32 adds ----------------
// Quarter q (16 lanes) owns node 4w+q; lane j covers cols 8j..8j+7.
__global__ __launch_bounds__(256) void k_agg(
    const unsigned int* __restrict__ xin,   // [N][64] bf16x2
    const int* __restrict__ rowptr,         // [NR+1], seg = dst*8 + rel
    const int* __restrict__ srcs,           // [E] sorted by seg
    unsigned int* __restrict__ Ag8,         // [8][srows][32] fp8x4
    int d0, int rows, int srows)
{
    const int t = threadIdx.x;
    const int wv = t >> 6, lane = t & 63;
    const int q = lane >> 4, j = lane & 15;
    const int nb0 = (blockIdx.x * 4 + wv) * 4;     // first local node of this wave
    if (nb0 >= rows) return;
    const int myn = nb0 + q;
    const bool nvalid = (myn < rows);

    // preload rowptr[(d0+nb0)*8 + lane] for lane<33 (clamped)
    int pr = 0;
    {
        int idx = (d0 + nb0) * 8 + lane;
        if (idx > NR) idx = NR;
        if (lane < 33) pr = rowptr[idx];
    }
    const int P0 = __shfl(pr, 0);
    const int Dtot = __shfl(pr, 32) - P0;

    // lane l holds srcs[P0+l] (first 64 edges of the 4 nodes, contiguous)
    int my_src = 0;
    if (lane < Dtot) my_src = srcs[P0 + lane];

    const uint4* x4 = (const uint4*)xin;           // row = 16 uint4

    for (int r = 0; r < 8; ++r) {
        int e0 = __shfl(pr, q * 8 + r);
        int e1 = __shfl(pr, q * 8 + r + 1);
        int cnt = e1 - e0;                         // quarter-uniform
        int m1 = max(cnt, __shfl_xor(cnt, 16));
        int maxc = max(m1, __shfl_xor(m1, 32));    // wave max
        float2v A0 = {0.f, 0.f}, A1 = {0.f, 0.f}, A2 = {0.f, 0.f}, A3 = {0.f, 0.f};
        int k = 0;
        for (; k + 2 <= maxc; k += 2) {
            int ei0 = e0 + k, ei1 = e0 + k + 1;
            int r0 = ei0 - P0, r1 = ei1 - P0;
            int s0 = __shfl(my_src, r0 & 63);
            int s1 = __shfl(my_src, r1 & 63);
            if (r0 >= 64) s0 = srcs[ei0];          // essentially never
            if (r1 >= 64) s1 = srcs[ei1];
            bool v0 = (k < cnt), v1 = (k + 1 < cnt);
            uint4 u0, u1;
            if (v0) u0 = x4[(size_t)s0 * 16 + j];
            if (v1) u1 = x4[(size_t)s1 * 16 + j];
            if (v0) {
                A0 += (float2v){bflo(u0.x), bfhi(u0.x)};
                A1 += (float2v){bflo(u0.y), bfhi(u0.y)};
                A2 += (float2v){bflo(u0.z), bfhi(u0.z)};
                A3 += (float2v){bflo(u0.w), bfhi(u0.w)};
            }
            if (v1) {
                A0 += (float2v){bflo(u1.x), bfhi(u1.x)};
                A1 += (float2v){bflo(u1.y), bfhi(u1.y)};
                A2 += (float2v){bflo(u1.z), bfhi(u1.z)};
                A3 += (float2v){bflo(u1.w), bfhi(u1.w)};
            }
        }
        if (k < maxc) {
            int ei = e0 + k;
            int ridx = ei - P0;
            int s = __shfl(my_src, ridx & 63);
            if (ridx >= 64) s = srcs[ei];
            if (k < cnt) {
                uint4 u = x4[(size_t)s * 16 + j];
                A0 += (float2v){bflo(u.x), bfhi(u.x)};
                A1 += (float2v){bflo(u.y), bfhi(u.y)};
                A2 += (float2v){bflo(u.z), bfhi(u.z)};
                A3 += (float2v){bflo(u.w), bfhi(u.w)};
            }
        }
        float inv = (cnt > 0) ? 1.0f / (float)cnt : 0.f;
        float2v iv = {inv, inv};
        A0 *= iv; A1 *= iv; A2 *= iv; A3 *= iv;
        int u0 = __builtin_amdgcn_cvt_pk_fp8_f32(A0.x, A0.y, 0, false);
        u0 = __builtin_amdgcn_cvt_pk_fp8_f32(A1.x, A1.y, u0, true);
        int u1 = __builtin_amdgcn_cvt_pk_fp8_f32(A2.x, A2.y, 0, false);
        u1 = __builtin_amdgcn_cvt_pk_fp8_f32(A3.x, A3.y, u1, true);
        if (nvalid) {
            uint2 v; v.x = (unsigned int)u0; v.y = (unsigned int)u1;
            *(uint2*)&Ag8[((size_t)r * srows + myn) * 32 + j * 2] = v;
        }
    }
}

// ---------------- dense MFMA GEMM, BM=128, 64 KB LDS, A reg-prefetch ----------------
#define BM 64
#define BM2 128
__global__ __launch_bounds__(256) void k_gemm(
    const unsigned int* __restrict__ Ag8,   // [8][srows][32] fp8x4
    const unsigned int* __restrict__ xin,   // [N][64] bf16x2 (root chunk)
    unsigned int* __restrict__ xout,        // [N][64] bf16x2
    const unsigned short* __restrict__ W8,  // [8][128n][64kp] fp8 pairs (this layer)
    const unsigned short* __restrict__ WT,  // [9][128n][128k] bf16 (this layer; root = chunk 8)
    const float* __restrict__ bias,         // [128]
    int d0, int srows)
{
    __shared__ __align__(16) ull Als[4096];  // 32 KB A region
    __shared__ __align__(16) ull Bls[4096];  // 32 KB B region
    const int t = threadIdx.x;
    const int wv = t >> 6, lane = t & 63;
    const int quad = lane >> 4, l15 = lane & 15;
    const int m0 = d0 + blockIdx.x * BM2;

    float4v acc[2][8];
#pragma unroll
    for (int nt = 0; nt < 8; ++nt) {
        float bc = bias[nt * 16 + l15];
        acc[0][nt] = (float4v){bc, bc, bc, bc};
        acc[1][nt] = (float4v){bc, bc, bc, bc};
    }

    // A chunk c lives at (c*srows + (m0-d0))*32 uints = that*... as ull: *16
    const ull* Abase = (const ull*)Ag8 + (size_t)(m0 - d0) * 16;
    const size_t cstride = (size_t)srows * 16;      // ull per chunk plane

    // prefetch chunk 0 into registers
    ull aR[8];
    {
        const ull* Ac = Abase;
#pragma unroll
        for (int i = 0; i < 8; ++i) aR[i] = Ac[t + 256 * i];
    }

    // ---- 8 fp8 chunks: A 128x128B (from regs), B 128x128B (global->LDS) ----
    for (int c = 0; c < 8; ++c) {
        __syncthreads();
        {
            const ull* Wc = (const ull*)(W8 + (size_t)c * 8192);
#pragma unroll
            for (int i = 0; i < 8; ++i) {
                int idx = t + 256 * i;            // 0..2047 granules
                Bls[gswz8(idx >> 4, idx & 15)] = Wc[idx];
            }
        }
#pragma unroll
        for (int i = 0; i < 8; ++i) {
            int idx = t + 256 * i;
            Als[gswz8(idx >> 4, idx & 15)] = aR[i];
        }
        __syncthreads();
        if (c < 7) {                               // overlap next-A loads with MFMA
            const ull* Ac = Abase + (size_t)(c + 1) * cstride;
#pragma unroll
            for (int i = 0; i < 8; ++i) aR[i] = Ac[t + 256 * i];
        }
#pragma unroll
        for (int kk = 0; kk < 4; ++kk) {
            int g = kk * 4 + quad;
            long long a0 = (long long)Als[(wv * 32 + l15) * 16 + (g ^ l15)];
            long long a1 = (long long)Als[(wv * 32 + 16 + l15) * 16 + (g ^ l15)];
#pragma unroll
            for (int nt = 0; nt < 8; ++nt) {
                long long b8 = (long long)Bls[(nt * 16 + l15) * 16 + (g ^ l15)];
                acc[0][nt] = __builtin_amdgcn_mfma_f32_16x16x32_fp8_fp8(a0, b8, acc[0][nt], 0, 0, 0);
                acc[1][nt] = __builtin_amdgcn_mfma_f32_16x16x32_fp8_fp8(a1, b8, acc[1][nt], 0, 0, 0);
            }
        }
    }
    // ---- root chunk (bf16): A = xin rows (32 KB), B = WT chunk 8 (32 KB) ----
    __syncthreads();
    {
        uint4* A4 = (uint4*)Als;
        uint4* B4 = (uint4*)Bls;
        const uint4* Wc = (const uint4*)(WT + 8 * 16384);   // 2048 uint4
#pragma unroll
        for (int i = 0; i < 8; ++i) {
            int idx = t + 256 * i;
            B4[gswz(idx >> 4, idx & 15)] = Wc[idx];
        }
        const uint4* Ac = (const uint4*)(xin + (size_t)m0 * 64);  // 128 rows x 16 uint4
#pragma unroll
        for (int i = 0; i < 8; ++i) {
            int idx = t + 256 * i;
            A4[gswz(idx >> 4, idx & 15)] = Ac[idx];
        }
    }
    __syncthreads();
    {
        const unsigned short* Abfs = (const unsigned short*)Als;
        const unsigned short* Bbfs = (const unsigned short*)Bls;
#pragma unroll
        for (int kk = 0; kk < 4; ++kk) {
            int g = kk * 4 + quad;
            short8 a0 = *(const short8*)(Abfs + gswz(wv * 32 + l15, g) * 8);
            short8 a1 = *(const short8*)(Abfs + gswz(wv * 32 + 16 + l15, g) * 8);
#pragma unroll
            for (int nt = 0; nt < 8; ++nt) {
                short8 b = *(const short8*)(Bbfs + gswz(nt * 16 + l15, g) * 8);
                acc[0][nt] = __builtin_amdgcn_mfma_f32_16x16x32_bf16(a0, b, acc[0][nt], 0, 0, 0);
                acc[1][nt] = __builtin_amdgcn_mfma_f32_16x16x32_bf16(a1, b, acc[1][nt], 0, 0, 0);
            }
        }
    }
    // ---- epilogue: relu, store bf16 ----
    unsigned short* outs = (unsigned short*)xout;
#pragma unroll
    for (int rt = 0; rt < 2; ++rt) {
#pragma unroll
        for (int nt = 0; nt < 8; ++nt) {
            int colg = nt * 16 + l15;
#pragma unroll
            for (int i = 0; i < 4; ++i) {
                int row = m0 + wv * 32 + rt * 16 + quad * 4 + i;
                if (row < N_NODES) {
                    float v = acc[rt][nt][i];
                    v = v > 0.f ? v : 0.f;
                    outs[(size_t)row * 128 + colg] = f2bf(v);
                }
            }
        }
    }
}

// ---------------- FALLBACK (fused layer; used only if ws too small) ----------------
__global__ __launch_bounds__(256) void k_layer_fb(
    const unsigned int* __restrict__ xin, unsigned int* __restrict__ xout,
    const int* __restrict__ rowptr, const int* __restrict__ srcs,
    const unsigned short* __restrict__ WT, const float* __restrict__ bias)
{
    __shared__ __align__(16) unsigned int Als[BM * 68];
    __shared__ __align__(16) unsigned int Bls[128 * 68];
    const int t = threadIdx.x;
    const int wv = t >> 6, lane = t & 63;
    const int quad = lane >> 4, l15 = lane & 15;
    const int m0 = blockIdx.x * BM;
    const int col2 = t & 63;
    const int rq = t >> 6;

    float4v acc[8];
#pragma unroll
    for (int nt = 0; nt < 8; ++nt) {
        float bc = bias[nt * 16 + l15];
        acc[nt] = (float4v){bc, bc, bc, bc};
    }
    for (int c = 0; c < 9; ++c) {
        if (c < 8) {
            for (int i = 0; i < 16; ++i) {
                int ml = rq + 4 * i;
                int m = m0 + ml;
                float a0 = 0.f, a1 = 0.f, inv = 0.f;
                if (m < N_NODES) {
                    int seg = m * N_REL + c;
                    int s = rowptr[seg], e = rowptr[seg + 1];
                    if (e > s) inv = 1.0f / (float)(e - s);
                    for (int jj = s; jj < e; ++jj) {
                        unsigned int u = xin[(size_t)srcs[jj] * 64 + col2];
                        a0 += bflo(u);
                        a1 += bfhi(u);
                    }
                }
                Als[ml * 68 + col2] = pack2(a0 * inv, a1 * inv);
            }
        } else {
            for (int i = 0; i < 16; ++i) {
                int ml = rq + 4 * i;
                int m = m0 + ml;
                Als[ml * 68 + col2] = (m < N_NODES) ? xin[(size_t)m * 64 + col2] : 0u;
            }
        }
        {
            const unsigned int* Wc = (const unsigned int*)(WT + c * 16384);
#pragma unroll
            for (int i = 0; i < 32; ++i) {
                int idx = t + 256 * i;
                Bls[(idx >> 6) * 68 + (idx & 63)] = Wc[idx];
            }
        }
        __syncthreads();
        const short* As = (const short*)Als;
        const short* Bs = (const short*)Bls;
#pragma unroll
        for (int kk = 0; kk < 4; ++kk) {
            short8 a = *(const short8*)(As + (wv * 16 + l15) * 136 + kk * 32 + quad * 8);
#pragma unroll
            for (int nt = 0; nt < 8; ++nt) {
                short8 b = *(const short8*)(Bs + (nt * 16 + l15) * 136 + kk * 32 + quad * 8);
                acc[nt] = __builtin_amdgcn_mfma_f32_16x16x32_bf16(a, b, acc[nt], 0, 0, 0);
            }
        }
        __syncthreads();
    }
    unsigned short* outs = (unsigned short*)xout;
#pragma unroll
    for (int nt = 0; nt < 8; ++nt) {
        int colg = nt * 16 + l15;
#pragma unroll
        for (int i = 0; i < 4; ++i) {
            int row = m0 + wv * 16 + quad * 4 + i;
            if (row < N_NODES) {
                float v = acc[nt][i];
                v = v > 0.f ? v : 0.f;
                outs[(size_t)row * 128 + colg] = f2bf(v);
            }
        }
    }
}

// ---------------- global mean pool (batch sorted): 64 nodes per wave ----------------
__global__ __launch_bounds__(256) void k_pool(const unsigned int* __restrict__ x2,
                                              const int* __restrict__ batch,
                                              float* __restrict__ gsum,
                                              int* __restrict__ gcnt) {
    const int wv = threadIdx.x >> 6, lane = threadIdx.x & 63;
    const int n0 = (blockIdx.x * 4 + wv) * 64;
    if (n0 >= N_NODES) return;
    int n1 = n0 + 64;
    if (n1 > N_NODES) n1 = N_NODES;
    const int nb = n1 - n0;
    int bb = batch[n0 + (lane < nb ? lane : nb - 1)];
    float a0 = 0.f, a1 = 0.f;
    int run = 0;
    int cur = __shfl(bb, 0);
    for (int base = 0; base < nb; base += 8) {
        unsigned int u[8];
        int m = nb - base;
#pragma unroll
        for (int qq = 0; qq < 8; ++qq)
            if (qq < m) u[qq] = x2[(size_t)(n0 + base + qq) * 64 + lane];
#pragma unroll
        for (int qq = 0; qq < 8; ++qq) {
            if (qq < m) {
                int b = __shfl(bb, base + qq);
                if (b != cur) {
                    atomicAdd(&gsum[cur * 128 + lane * 2], a0);
                    atomicAdd(&gsum[cur * 128 + lane * 2 + 1], a1);
                    if (lane == 0) atomicAdd(&gcnt[cur], run);
                    a0 = a1 = 0.f;
                    run = 0;
                    cur = b;
                }
                a0 += bflo(u[qq]);
                a1 += bfhi(u[qq]);
                ++run;
            }
        }
    }
    atomicAdd(&gsum[cur * 128 + lane * 2], a0);
    atomicAdd(&gsum[cur * 128 + lane * 2 + 1], a1);
    if (lane == 0) atomicAdd(&gcnt[cur], run);
}

// ---------------- MLP heads (fp32) ----------------
__global__ __launch_bounds__(128) void k_heads(
    const float* __restrict__ gsum, const int* __restrict__ gcnt,
    const float* __restrict__ rw1, const float* __restrict__ rb1,
    const float* __restrict__ rw2, const float* __restrict__ rb2,
    const float* __restrict__ sw1, const float* __restrict__ sb1,
    const float* __restrict__ sw2, const float* __restrict__ sb2,
    float* __restrict__ out) {
    __shared__ float g[128];
    __shared__ float parts[2];
    int b = blockIdx.x, t = threadIdx.x;
    int c = gcnt[b];
    float invc = 1.0f / (float)(c > 0 ? c : 1);
    g[t] = gsum[b * 128 + t] * invc;
    __syncthreads();
    float acc = rb1[t];
    for (int d = 0; d < 128; ++d) acc += g[d] * rw1[d * 128 + t];
    float h = acc > 0.f ? acc : 0.f;
    float p = h * rw2[t];
    for (int o = 32; o > 0; o >>= 1) p += __shfl_down(p, o);
    if ((t & 63) == 0) parts[t >> 6] = p;
    __syncthreads();
    if (t == 0) out[b] = parts[0] + parts[1] + rb2[0];
    __syncthreads();
    acc = sb1[t];
    for (int d = 0; d < 128; ++d) acc += g[d] * sw1[d * 128 + t];
    h = acc > 0.f ? acc : 0.f;
    p = h * sw2[t];
    for (int o = 32; o > 0; o >>= 1) p += __shfl_down(p, o);
    if ((t & 63) == 0) parts[t >> 6] = p;
    __syncthreads();
    if (t == 0) out[64 + b] = parts[0] + parts[1] + sb2[0];
}

extern "C" void kernel_launch(void* const* d_in, const int* in_sizes, int n_in,
                              void* d_out, int out_size, void* d_ws, size_t ws_size,
                              hipStream_t stream) {
    const int*   node_type  = (const int*)d_in[0];
    const int*   edge_index = (const int*)d_in[1];
    const int*   edge_type  = (const int*)d_in[2];
    const int*   batch      = (const int*)d_in[3];
    const float* node_emb   = (const float*)d_in[4];
    const float* rel_w      = (const float*)d_in[5];
    const float* root_w     = (const float*)d_in[6];
    const float* bias       = (const float*)d_in[7];
    const float* rw1        = (const float*)d_in[8];
    const float* rb1        = (const float*)d_in[9];
    const float* rw2        = (const float*)d_in[10];
    const float* rb2        = (const float*)d_in[11];
    const float* sw1        = (const float*)d_in[12];
    const float* sb1        = (const float*)d_in[13];
    const float* sw2        = (const float*)d_in[14];
    const float* sb2        = (const float*)d_in[15];
    float* out = (float*)d_out;

    char* ws = (char*)d_ws;
    size_t off = 0;
    auto alloc = [&](size_t bytes) -> void* {
        void* p = ws + off;
        off += (bytes + 255) & ~(size_t)255;
        return p;
    };
    // ---- persistent region ----
    unsigned int*   xa     = (unsigned int*)alloc((size_t)N_NODES * 64 * 4);
    unsigned int*   xb     = (unsigned int*)alloc((size_t)N_NODES * 64 * 4);
    int*            rowptr = (int*)alloc((size_t)(NR + 1) * 4);
    int*            srcs   = (int*)alloc((size_t)N_EDGES * 4);
    int*            bsum   = (int*)alloc(1024 * 4);
    unsigned short* WT     = (unsigned short*)alloc((size_t)N_LAYER * 9 * 16384 * 2);
    unsigned short* W8     = (unsigned short*)alloc((size_t)N_LAYER * 8 * 8192 * 2);
    float*          gsum   = (float*)alloc((64 * 128 + 64) * 4);
    int*            gcnt   = (int*)(gsum + 64 * 128);
    size_t off_common = off;
    // ---- scratch region: sort temps, later overlapped by Ag8 slices ----
    int*            cursor = (int*)alloc((size_t)NR * 4);
    int*            counts = (int*)alloc((size_t)NR * 4);
    size_t off_sort = off;
    if (off_sort > ws_size) return;                // cannot run at all
    unsigned int*   Ag8    = (unsigned int*)(ws + off_common);  // overlaps cursor/counts
    size_t avail = ws_size - off_common;
    long max_rows = (avail > 32768) ? (long)((avail - 32768) / 1024) : 0;  // 32 KB tail-read slack
    int srows = (int)((max_rows / 64) * 64);
    if (srows > N_NODES + 63) srows = ((N_NODES + 63) / 64) * 64;
    const bool split_ok = (srows >= 128);

    // edge sort (counting sort by dst*8 + rel)
    k_zero<<<(NR + 255) / 256, 256, 0, stream>>>(counts, NR);
    k_zero<<<(64 * 128 + 64 + 255) / 256, 256, 0, stream>>>((int*)gsum, 64 * 128 + 64);
    k_hist<<<(N_EDGES + 255) / 256, 256, 0, stream>>>(edge_index, edge_type, counts);
    k_scan1<<<NB1, 256, 0, stream>>>(counts, cursor, bsum);
    k_scan2<<<1, 1024, 0, stream>>>(bsum, NB1);
    k_scan3<<<(NR + 255) / 256, 256, 0, stream>>>(cursor, bsum, rowptr, cursor);
    k_scatter<<<(N_EDGES + 255) / 256, 256, 0, stream>>>(edge_index, edge_type, cursor, srcs);

    // x0 gather + weight prep (bf16 + fp8)
    k_gather<<<(N_NODES * 64 + 255) / 256, 256, 0, stream>>>(node_type, node_emb, xa);
    k_wprep<<<(N_LAYER * 9 * 16384 + 255) / 256, 256, 0, stream>>>(rel_w, root_w, WT);
    k_wprep8<<<(N_LAYER * 8 * 8192 + 255) / 256, 256, 0, stream>>>(rel_w, W8);

    const int mblocks = (N_NODES + BM - 1) / BM;   // 1563 (fallback)
    unsigned int* xcur = xa;
    unsigned int* xnext = xb;
    for (int l = 0; l < N_LAYER; ++l) {
        const unsigned short* Wl  = WT + (size_t)l * 9 * 16384;
        const unsigned short* W8l = W8 + (size_t)l * 8 * 8192;
        const float* bl = bias + (size_t)l * 128;
        if (split_ok) {
            for (int d0 = 0; d0 < N_NODES; d0 += srows) {
                int rows = N_NODES - d0;
                if (rows > srows) rows = srows;
                int ab = (rows + 15) / 16;                 // 16 nodes per block (4 waves x 4)
                int gb = (rows + BM2 - 1) / BM2;
                k_agg<<<ab, 256, 0, stream>>>(xcur, rowptr, srcs, Ag8, d0, rows, srows);
                k_gemm<<<gb, 256, 0, stream>>>(Ag8, xcur, xnext, W8l, Wl, bl, d0, srows);
            }
        } else {
            k_layer_fb<<<mblocks, 256, 0, stream>>>(xcur, xnext, rowptr, srcs, Wl, bl);
        }
        unsigned int* tmp = xcur; xcur = xnext; xnext = tmp;
    }

    // pool + heads (final activations are in xcur after swap)
    k_pool<<<(N_NODES + 255) / 256, 256, 0, stream>>>(xcur, batch, gsum, gcnt);
    k_heads<<<64, 128, 0, stream>>>(gsum, gcnt, rw1, rb1, rw2, rb2,
                                    sw1, sb1, sw2, sb2, out);
}

// Round 12
// 459.149 us; speedup vs baseline: 1.4360x; 1.0525x over previous
//
#include <hip/hip_runtime.h>
#include <hip/hip_bf16.h>

#define N_NODES 100000
#define N_EDGES 600000
#define DIM     128
#define N_REL   8
#define N_GRAPH 64
#define N_LAYER 3
#define NR      (N_NODES * N_REL)   // 800000
#define NB1     782                 // ceil(NR / 1024)

typedef __attribute__((ext_vector_type(8))) short short8;
typedef __attribute__((ext_vector_type(4))) float float4v;
typedef __attribute__((ext_vector_type(2))) float float2v;
typedef unsigned long long ull;

__device__ __forceinline__ float bflo(unsigned int u) {
    return __builtin_bit_cast(float, u << 16);
}
__device__ __forceinline__ float bfhi(unsigned int u) {
    return __builtin_bit_cast(float, u & 0xffff0000u);
}
__device__ __forceinline__ unsigned short f2bf(float f) {
    unsigned int u = __builtin_bit_cast(unsigned int, f);
    u += 0x7fffu + ((u >> 16) & 1u);          // RNE
    return (unsigned short)(u >> 16);
}
__device__ __forceinline__ unsigned int pack2(float a, float b) {
    return (unsigned int)f2bf(a) | ((unsigned int)f2bf(b) << 16);
}
// XOR-swizzle, 8-B granules, 128-B rows (fp8 tiles): 16 granules/row
__device__ __forceinline__ int gswz8(int row, int g) {
    return row * 16 + (g ^ (row & 15));
}
// XOR-swizzle, 16-B granules, 256-B rows (bf16 tiles): 16 granules/row
__device__ __forceinline__ int gswz(int row, int g) {
    return row * 16 + (g ^ (row & 15));
}

// ---------------- counting sort of edges by seg = dst*8 + rel (dst-major) ----------------
__global__ void k_hist(const int* __restrict__ ei, const int* __restrict__ et,
                       int* __restrict__ counts) {
    int e = blockIdx.x * 256 + threadIdx.x;
    if (e < N_EDGES) {
        int seg = ei[N_EDGES + e] * N_REL + et[e];
        atomicAdd(&counts[seg], 1);
    }
}

__global__ __launch_bounds__(256) void k_scan1(const int* __restrict__ cnts,
                                               int* __restrict__ part,
                                               int* __restrict__ bsum) {
    __shared__ int sh[256];
    int t = threadIdx.x;
    int base = blockIdx.x * 1024 + t * 4;
    int v0 = (base + 0 < NR) ? cnts[base + 0] : 0;
    int v1 = (base + 1 < NR) ? cnts[base + 1] : 0;
    int v2 = (base + 2 < NR) ? cnts[base + 2] : 0;
    int v3 = (base + 3 < NR) ? cnts[base + 3] : 0;
    int tot = v0 + v1 + v2 + v3;
    sh[t] = tot;
    __syncthreads();
    for (int off = 1; off < 256; off <<= 1) {
        int x = (t >= off) ? sh[t - off] : 0;
        __syncthreads();
        sh[t] += x;
        __syncthreads();
    }
    int exc = sh[t] - tot;
    if (base + 0 < NR) part[base + 0] = exc;
    if (base + 1 < NR) part[base + 1] = exc + v0;
    if (base + 2 < NR) part[base + 2] = exc + v0 + v1;
    if (base + 3 < NR) part[base + 3] = exc + v0 + v1 + v2;
    if (t == 255) bsum[blockIdx.x] = sh[t];
}

__global__ __launch_bounds__(1024) void k_scan2(int* __restrict__ bsum, int nb) {
    __shared__ int sh[1024];
    int t = threadIdx.x;
    int v = (t < nb) ? bsum[t] : 0;
    sh[t] = v;
    __syncthreads();
    for (int off = 1; off < 1024; off <<= 1) {
        int x = (t >= off) ? sh[t - off] : 0;
        __syncthreads();
        sh[t] += x;
        __syncthreads();
    }
    if (t < nb) bsum[t] = sh[t] - v;   // exclusive block offsets
}

__global__ void k_scan3(const int* __restrict__ part, const int* __restrict__ bsum,
                        int* __restrict__ rowptr, int* __restrict__ cursor) {
    int i = blockIdx.x * 256 + threadIdx.x;
    if (i < NR) {
        int v = part[i] + bsum[i >> 10];
        rowptr[i] = v;
        cursor[i] = v;
    }
    if (i == 0) rowptr[NR] = N_EDGES;
}

__global__ void k_scatter(const int* __restrict__ ei, const int* __restrict__ et,
                          int* __restrict__ cursor, int* __restrict__ srcs) {
    int e = blockIdx.x * 256 + threadIdx.x;
    if (e < N_EDGES) {
        int seg = ei[N_EDGES + e] * N_REL + et[e];
        int p = atomicAdd(&cursor[seg], 1);
        srcs[p] = ei[e];
    }
}

// ---------------- x0 = node_emb[node_type], stored bf16x2 ----------------
__global__ void k_gather(const int* __restrict__ nt, const float* __restrict__ emb,
                         unsigned int* __restrict__ x2) {
    int gid = blockIdx.x * 256 + threadIdx.x;
    if (gid < N_NODES * 64) {
        int n = gid >> 6, c2 = gid & 63;
        const float* row = emb + (size_t)nt[n] * DIM + c2 * 2;
        x2[gid] = pack2(row[0], row[1]);
    }
}

// ---------------- weight prep (merged): bf16 WT + fp8 W8 ----------------
#define WT_TOTAL (N_LAYER * 9 * 16384)
#define W8_TOTAL (N_LAYER * 8 * 8192)
__global__ void k_wprep_all(const float* __restrict__ relw, const float* __restrict__ rootw,
                            unsigned short* __restrict__ WT, unsigned short* __restrict__ W8) {
    int gid = blockIdx.x * 256 + threadIdx.x;
    if (gid < WT_TOTAL) {
        int l = gid / (9 * 16384);
        int rem = gid - l * 9 * 16384;
        int c = rem >> 14;
        int idx = rem & 16383;
        int n = idx >> 7, k = idx & 127;
        float w = (c < 8) ? relw[(((size_t)l * 8 + c) * 128 + k) * 128 + n]
                          : rootw[((size_t)l * 128 + k) * 128 + n];
        WT[gid] = f2bf(w);
    } else if (gid < WT_TOTAL + W8_TOTAL) {
        int g2 = gid - WT_TOTAL;
        int l = g2 / (8 * 8192);
        int rem = g2 - l * 8 * 8192;
        int r = rem >> 13;
        int idx = rem & 8191;
        int n = idx >> 6, kp = idx & 63;
        const float* base = relw + (((size_t)(l * 8 + r) * 128) * 128) + n;
        float w0 = base[(size_t)(2 * kp) * 128];
        float w1 = base[(size_t)(2 * kp + 1) * 128];
        int pk = __builtin_amdgcn_cvt_pk_fp8_f32(w0, w1, 0, false);
        W8[g2] = (unsigned short)(pk & 0xffff);
    }
}

// ---------------- per-dst aggregation: 4 nodes per wave, fp8 out ----------------
// Quarter q (16 lanes) owns node 4w+q; lane j covers cols 8j..8j+7.
__global__ __launch_bounds__(256) void k_agg(
    const unsigned int* __restrict__ xin,   // [N][64] bf16x2
    const int* __restrict__ rowptr,         // [NR+1], seg = dst*8 + rel
    const int* __restrict__ srcs,           // [E] sorted by seg
    unsigned int* __restrict__ Ag8,         // [8][srows][32] fp8x4
    int d0, int rows, int srows)
{
    const int t = threadIdx.x;
    const int wv = t >> 6, lane = t & 63;
    const int q = lane >> 4, j = lane & 15;
    const int nb0 = (blockIdx.x * 4 + wv) * 4;     // first local node of this wave
    if (nb0 >= rows) return;
    const int myn = nb0 + q;
    const bool nvalid = (myn < rows);

    // preload rowptr[(d0+nb0)*8 + lane] for lane<33 (clamped)
    int pr = 0;
    {
        int idx = (d0 + nb0) * 8 + lane;
        if (idx > NR) idx = NR;
        if (lane < 33) pr = rowptr[idx];
    }
    const int P0 = __shfl(pr, 0);
    const int Dtot = __shfl(pr, 32) - P0;

    // lane l holds srcs[P0+l] (first 64 edges of the 4 nodes, contiguous)
    int my_src = 0;
    if (lane < Dtot) my_src = srcs[P0 + lane];

    const uint4* x4 = (const uint4*)xin;           // row = 16 uint4

    for (int r = 0; r < 8; ++r) {
        int e0 = __shfl(pr, q * 8 + r);
        int e1 = __shfl(pr, q * 8 + r + 1);
        int cnt = e1 - e0;                         // quarter-uniform
        int m1 = max(cnt, __shfl_xor(cnt, 16));
        int maxc = max(m1, __shfl_xor(m1, 32));    // wave max
        float2v A0 = {0.f, 0.f}, A1 = {0.f, 0.f}, A2 = {0.f, 0.f}, A3 = {0.f, 0.f};
        int k = 0;
        for (; k + 2 <= maxc; k += 2) {
            int ei0 = e0 + k, ei1 = e0 + k + 1;
            int r0 = ei0 - P0, r1 = ei1 - P0;
            int s0 = __shfl(my_src, r0 & 63);
            int s1 = __shfl(my_src, r1 & 63);
            if (r0 >= 64) s0 = srcs[ei0];          // essentially never
            if (r1 >= 64) s1 = srcs[ei1];
            bool v0 = (k < cnt), v1 = (k + 1 < cnt);
            uint4 u0, u1;
            if (v0) u0 = x4[(size_t)s0 * 16 + j];
            if (v1) u1 = x4[(size_t)s1 * 16 + j];
            if (v0) {
                A0 += (float2v){bflo(u0.x), bfhi(u0.x)};
                A1 += (float2v){bflo(u0.y), bfhi(u0.y)};
                A2 += (float2v){bflo(u0.z), bfhi(u0.z)};
                A3 += (float2v){bflo(u0.w), bfhi(u0.w)};
            }
            if (v1) {
                A0 += (float2v){bflo(u1.x), bfhi(u1.x)};
                A1 += (float2v){bflo(u1.y), bfhi(u1.y)};
                A2 += (float2v){bflo(u1.z), bfhi(u1.z)};
                A3 += (float2v){bflo(u1.w), bfhi(u1.w)};
            }
        }
        if (k < maxc) {
            int ei = e0 + k;
            int ridx = ei - P0;
            int s = __shfl(my_src, ridx & 63);
            if (ridx >= 64) s = srcs[ei];
            if (k < cnt) {
                uint4 u = x4[(size_t)s * 16 + j];
                A0 += (float2v){bflo(u.x), bfhi(u.x)};
                A1 += (float2v){bflo(u.y), bfhi(u.y)};
                A2 += (float2v){bflo(u.z), bfhi(u.z)};
                A3 += (float2v){bflo(u.w), bfhi(u.w)};
            }
        }
        float inv = (cnt > 0) ? 1.0f / (float)cnt : 0.f;
        float2v iv = {inv, inv};
        A0 *= iv; A1 *= iv; A2 *= iv; A3 *= iv;
        int u0 = __builtin_amdgcn_cvt_pk_fp8_f32(A0.x, A0.y, 0, false);
        u0 = __builtin_amdgcn_cvt_pk_fp8_f32(A1.x, A1.y, u0, true);
        int u1 = __builtin_amdgcn_cvt_pk_fp8_f32(A2.x, A2.y, 0, false);
        u1 = __builtin_amdgcn_cvt_pk_fp8_f32(A3.x, A3.y, u1, true);
        if (nvalid) {
            uint2 v; v.x = (unsigned int)u0; v.y = (unsigned int)u1;
            *(uint2*)&Ag8[((size_t)r * srows + myn) * 32 + j * 2] = v;
        }
    }
}

// ---------------- dense MFMA GEMM, BM=128, ping-pong LDS, 1 barrier/chunk ----------------
#define BM 64
#define BM2 128
__global__ __launch_bounds__(256) void k_gemm(
    const unsigned int* __restrict__ Ag8,   // [8][srows][32] fp8x4
    const unsigned int* __restrict__ xin,   // [N][64] bf16x2 (root chunk)
    unsigned int* __restrict__ xout,        // [N][64] bf16x2
    const unsigned short* __restrict__ W8,  // [8][128n][64kp] fp8 pairs (this layer)
    const unsigned short* __restrict__ WT,  // [9][128n][128k] bf16 (this layer; root = chunk 8)
    const float* __restrict__ bias,         // [128]
    int d0, int srows)
{
    __shared__ __align__(16) ull Als[4096];  // 32 KB: fp8 dbuf [2][2048]; root full
    __shared__ __align__(16) ull Bls[4096];  // 32 KB: fp8 dbuf [2][2048]; root full
    const int t = threadIdx.x;
    const int wv = t >> 6, lane = t & 63;
    const int quad = lane >> 4, l15 = lane & 15;
    const int m0 = d0 + blockIdx.x * BM2;

    float4v acc[2][8];
#pragma unroll
    for (int nt = 0; nt < 8; ++nt) {
        float bc = bias[nt * 16 + l15];
        acc[0][nt] = (float4v){bc, bc, bc, bc};
        acc[1][nt] = (float4v){bc, bc, bc, bc};
    }

    const ull* Abase = (const ull*)Ag8 + (size_t)(m0 - d0) * 16;
    const size_t cstride = (size_t)srows * 16;      // ull per chunk plane

    // prefetch chunk 0 (A and B) into registers, write into buf 0
    ull aR[8], bR[8];
    {
        const ull* Ac = Abase;
        const ull* Wc = (const ull*)W8;
#pragma unroll
        for (int i = 0; i < 8; ++i) {
            aR[i] = Ac[t + 256 * i];
            bR[i] = Wc[t + 256 * i];
        }
    }
#pragma unroll
    for (int i = 0; i < 8; ++i) {
        int idx = t + 256 * i;
        int sw = gswz8(idx >> 4, idx & 15);
        Als[sw] = aR[i];
        Bls[sw] = bR[i];
    }
    __syncthreads();

    // ---- 8 fp8 chunks, ping-pong, single barrier per chunk ----
    for (int c = 0; c < 8; ++c) {
        const int cur = (c & 1) * 2048;
        if (c < 7) {                               // issue next-chunk loads (hidden by MFMA)
            const ull* Ac = Abase + (size_t)(c + 1) * cstride;
            const ull* Wc = (const ull*)(W8 + (size_t)(c + 1) * 8192);
#pragma unroll
            for (int i = 0; i < 8; ++i) {
                aR[i] = Ac[t + 256 * i];
                bR[i] = Wc[t + 256 * i];
            }
        }
#pragma unroll
        for (int kk = 0; kk < 4; ++kk) {
            int g = kk * 4 + quad;
            long long a0 = (long long)Als[cur + (wv * 32 + l15) * 16 + (g ^ l15)];
            long long a1 = (long long)Als[cur + (wv * 32 + 16 + l15) * 16 + (g ^ l15)];
#pragma unroll
            for (int nt = 0; nt < 8; ++nt) {
                long long b8 = (long long)Bls[cur + (nt * 16 + l15) * 16 + (g ^ l15)];
                acc[0][nt] = __builtin_amdgcn_mfma_f32_16x16x32_fp8_fp8(a0, b8, acc[0][nt], 0, 0, 0);
                acc[1][nt] = __builtin_amdgcn_mfma_f32_16x16x32_fp8_fp8(a1, b8, acc[1][nt], 0, 0, 0);
            }
        }
        if (c < 7) {                               // write prefetched data into other buf
            const int nxt = ((c + 1) & 1) * 2048;
#pragma unroll
            for (int i = 0; i < 8; ++i) {
                int idx = t + 256 * i;
                int sw = gswz8(idx >> 4, idx & 15);
                Als[nxt + sw] = aR[i];
                Bls[nxt + sw] = bR[i];
            }
        }
        __syncthreads();
    }
    // ---- root chunk (bf16): A = xin rows (32 KB), B = WT chunk 8 (32 KB) ----
    {
        uint4* A4 = (uint4*)Als;
        uint4* B4 = (uint4*)Bls;
        const uint4* Wc = (const uint4*)(WT + 8 * 16384);   // 2048 uint4
        const uint4* Ac = (const uint4*)(xin + (size_t)m0 * 64);  // 128 rows x 16 uint4
#pragma unroll
        for (int i = 0; i < 8; ++i) {
            int idx = t + 256 * i;
            int sw = gswz(idx >> 4, idx & 15);
            B4[sw] = Wc[idx];
            A4[sw] = Ac[idx];
        }
    }
    __syncthreads();
    {
        const unsigned short* Abfs = (const unsigned short*)Als;
        const unsigned short* Bbfs = (const unsigned short*)Bls;
#pragma unroll
        for (int kk = 0; kk < 4; ++kk) {
            int g = kk * 4 + quad;
            short8 a0 = *(const short8*)(Abfs + gswz(wv * 32 + l15, g) * 8);
            short8 a1 = *(const short8*)(Abfs + gswz(wv * 32 + 16 + l15, g) * 8);
#pragma unroll
            for (int nt = 0; nt < 8; ++nt) {
                short8 b = *(const short8*)(Bbfs + gswz(nt * 16 + l15, g) * 8);
                acc[0][nt] = __builtin_amdgcn_mfma_f32_16x16x32_bf16(a0, b, acc[0][nt], 0, 0, 0);
                acc[1][nt] = __builtin_amdgcn_mfma_f32_16x16x32_bf16(a1, b, acc[1][nt], 0, 0, 0);
            }
        }
    }
    // ---- epilogue: relu, store bf16 ----
    unsigned short* outs = (unsigned short*)xout;
#pragma unroll
    for (int rt = 0; rt < 2; ++rt) {
#pragma unroll
        for (int nt = 0; nt < 8; ++nt) {
            int colg = nt * 16 + l15;
#pragma unroll
            for (int i = 0; i < 4; ++i) {
                int row = m0 + wv * 32 + rt * 16 + quad * 4 + i;
                if (row < N_NODES) {
                    float v = acc[rt][nt][i];
                    v = v > 0.f ? v : 0.f;
                    outs[(size_t)row * 128 + colg] = f2bf(v);
                }
            }
        }
    }
}

// ---------------- FALLBACK (fused layer; used only if ws too small) ----------------
__global__ __launch_bounds__(256) void k_layer_fb(
    const unsigned int* __restrict__ xin, unsigned int* __restrict__ xout,
    const int* __restrict__ rowptr, const int* __restrict__ srcs,
    const unsigned short* __restrict__ WT, const float* __restrict__ bias)
{
    __shared__ __align__(16) unsigned int Als[BM * 68];
    __shared__ __align__(16) unsigned int Bls[128 * 68];
    const int t = threadIdx.x;
    const int wv = t >> 6, lane = t & 63;
    const int quad = lane >> 4, l15 = lane & 15;
    const int m0 = blockIdx.x * BM;
    const int col2 = t & 63;
    const int rq = t >> 6;

    float4v acc[8];
#pragma unroll
    for (int nt = 0; nt < 8; ++nt) {
        float bc = bias[nt * 16 + l15];
        acc[nt] = (float4v){bc, bc, bc, bc};
    }
    for (int c = 0; c < 9; ++c) {
        if (c < 8) {
            for (int i = 0; i < 16; ++i) {
                int ml = rq + 4 * i;
                int m = m0 + ml;
                float a0 = 0.f, a1 = 0.f, inv = 0.f;
                if (m < N_NODES) {
                    int seg = m * N_REL + c;
                    int s = rowptr[seg], e = rowptr[seg + 1];
                    if (e > s) inv = 1.0f / (float)(e - s);
                    for (int jj = s; jj < e; ++jj) {
                        unsigned int u = xin[(size_t)srcs[jj] * 64 + col2];
                        a0 += bflo(u);
                        a1 += bfhi(u);
                    }
                }
                Als[ml * 68 + col2] = pack2(a0 * inv, a1 * inv);
            }
        } else {
            for (int i = 0; i < 16; ++i) {
                int ml = rq + 4 * i;
                int m = m0 + ml;
                Als[ml * 68 + col2] = (m < N_NODES) ? xin[(size_t)m * 64 + col2] : 0u;
            }
        }
        {
            const unsigned int* Wc = (const unsigned int*)(WT + c * 16384);
#pragma unroll
            for (int i = 0; i < 32; ++i) {
                int idx = t + 256 * i;
                Bls[(idx >> 6) * 68 + (idx & 63)] = Wc[idx];
            }
        }
        __syncthreads();
        const short* As = (const short*)Als;
        const short* Bs = (const short*)Bls;
#pragma unroll
        for (int kk = 0; kk < 4; ++kk) {
            short8 a = *(const short8*)(As + (wv * 16 + l15) * 136 + kk * 32 + quad * 8);
#pragma unroll
            for (int nt = 0; nt < 8; ++nt) {
                short8 b = *(const short8*)(Bs + (nt * 16 + l15) * 136 + kk * 32 + quad * 8);
                acc[nt] = __builtin_amdgcn_mfma_f32_16x16x32_bf16(a, b, acc[nt], 0, 0, 0);
            }
        }
        __syncthreads();
    }
    unsigned short* outs = (unsigned short*)xout;
#pragma unroll
    for (int nt = 0; nt < 8; ++nt) {
        int colg = nt * 16 + l15;
#pragma unroll
        for (int i = 0; i < 4; ++i) {
            int row = m0 + wv * 16 + quad * 4 + i;
            if (row < N_NODES) {
                float v = acc[nt][i];
                v = v > 0.f ? v : 0.f;
                outs[(size_t)row * 128 + colg] = f2bf(v);
            }
        }
    }
}

// ---------------- global mean pool (batch sorted): 64 nodes per wave ----------------
__global__ __launch_bounds__(256) void k_pool(const unsigned int* __restrict__ x2,
                                              const int* __restrict__ batch,
                                              float* __restrict__ gsum,
                                              int* __restrict__ gcnt) {
    const int wv = threadIdx.x >> 6, lane = threadIdx.x & 63;
    const int n0 = (blockIdx.x * 4 + wv) * 64;
    if (n0 >= N_NODES) return;
    int n1 = n0 + 64;
    if (n1 > N_NODES) n1 = N_NODES;
    const int nb = n1 - n0;
    int bb = batch[n0 + (lane < nb ? lane : nb - 1)];
    float a0 = 0.f, a1 = 0.f;
    int run = 0;
    int cur = __shfl(bb, 0);
    for (int base = 0; base < nb; base += 8) {
        unsigned int u[8];
        int m = nb - base;
#pragma unroll
        for (int qq = 0; qq < 8; ++qq)
            if (qq < m) u[qq] = x2[(size_t)(n0 + base + qq) * 64 + lane];
#pragma unroll
        for (int qq = 0; qq < 8; ++qq) {
            if (qq < m) {
                int b = __shfl(bb, base + qq);
                if (b != cur) {
                    atomicAdd(&gsum[cur * 128 + lane * 2], a0);
                    atomicAdd(&gsum[cur * 128 + lane * 2 + 1], a1);
                    if (lane == 0) atomicAdd(&gcnt[cur], run);
                    a0 = a1 = 0.f;
                    run = 0;
                    cur = b;
                }
                a0 += bflo(u[qq]);
                a1 += bfhi(u[qq]);
                ++run;
            }
        }
    }
    atomicAdd(&gsum[cur * 128 + lane * 2], a0);
    atomicAdd(&gsum[cur * 128 + lane * 2 + 1], a1);
    if (lane == 0) atomicAdd(&gcnt[cur], run);
}

// ---------------- MLP heads (fp32) ----------------
__global__ __launch_bounds__(128) void k_heads(
    const float* __restrict__ gsum, const int* __restrict__ gcnt,
    const float* __restrict__ rw1, const float* __restrict__ rb1,
    const float* __restrict__ rw2, const float* __restrict__ rb2,
    const float* __restrict__ sw1, const float* __restrict__ sb1,
    const float* __restrict__ sw2, const float* __restrict__ sb2,
    float* __restrict__ out) {
    __shared__ float g[128];
    __shared__ float parts[2];
    int b = blockIdx.x, t = threadIdx.x;
    int c = gcnt[b];
    float invc = 1.0f / (float)(c > 0 ? c : 1);
    g[t] = gsum[b * 128 + t] * invc;
    __syncthreads();
    float acc = rb1[t];
    for (int d = 0; d < 128; ++d) acc += g[d] * rw1[d * 128 + t];
    float h = acc > 0.f ? acc : 0.f;
    float p = h * rw2[t];
    for (int o = 32; o > 0; o >>= 1) p += __shfl_down(p, o);
    if ((t & 63) == 0) parts[t >> 6] = p;
    __syncthreads();
    if (t == 0) out[b] = parts[0] + parts[1] + rb2[0];
    __syncthreads();
    acc = sb1[t];
    for (int d = 0; d < 128; ++d) acc += g[d] * sw1[d * 128 + t];
    h = acc > 0.f ? acc : 0.f;
    p = h * sw2[t];
    for (int o = 32; o > 0; o >>= 1) p += __shfl_down(p, o);
    if ((t & 63) == 0) parts[t >> 6] = p;
    __syncthreads();
    if (t == 0) out[64 + b] = parts[0] + parts[1] + sb2[0];
}

extern "C" void kernel_launch(void* const* d_in, const int* in_sizes, int n_in,
                              void* d_out, int out_size, void* d_ws, size_t ws_size,
                              hipStream_t stream) {
    const int*   node_type  = (const int*)d_in[0];
    const int*   edge_index = (const int*)d_in[1];
    const int*   edge_type  = (const int*)d_in[2];
    const int*   batch      = (const int*)d_in[3];
    const float* node_emb   = (const float*)d_in[4];
    const float* rel_w      = (const float*)d_in[5];
    const float* root_w     = (const float*)d_in[6];
    const float* bias       = (const float*)d_in[7];
    const float* rw1        = (const float*)d_in[8];
    const float* rb1        = (const float*)d_in[9];
    const float* rw2        = (const float*)d_in[10];
    const float* rb2        = (const float*)d_in[11];
    const float* sw1        = (const float*)d_in[12];
    const float* sb1        = (const float*)d_in[13];
    const float* sw2        = (const float*)d_in[14];
    const float* sb2        = (const float*)d_in[15];
    float* out = (float*)d_out;

    char* ws = (char*)d_ws;
    size_t off = 0;
    auto alloc = [&](size_t bytes) -> void* {
        void* p = ws + off;
        off += (bytes + 255) & ~(size_t)255;
        return p;
    };
    // ---- persistent region ----
    unsigned int*   xa     = (unsigned int*)alloc((size_t)N_NODES * 64 * 4);
    unsigned int*   xb     = (unsigned int*)alloc((size_t)N_NODES * 64 * 4);
    int*            rowptr = (int*)alloc((size_t)(NR + 1) * 4);
    int*            srcs   = (int*)alloc((size_t)N_EDGES * 4);
    int*            bsum   = (int*)alloc(1024 * 4);
    unsigned short* WT     = (unsigned short*)alloc((size_t)WT_TOTAL * 2);
    unsigned short* W8     = (unsigned short*)alloc((size_t)W8_TOTAL * 2);
    float*          gsum   = (float*)alloc((64 * 128 + 64) * 4);
    int*            gcnt   = (int*)(gsum + 64 * 128);
    size_t off_common = off;
    // ---- scratch region: sort temps, later overlapped by Ag8 slices ----
    int*            cursor = (int*)alloc((size_t)NR * 4);
    int*            counts = (int*)alloc((size_t)NR * 4);
    size_t off_sort = off;
    if (off_sort > ws_size) return;                // cannot run at all
    unsigned int*   Ag8    = (unsigned int*)(ws + off_common);  // overlaps cursor/counts
    size_t avail = ws_size - off_common;
    long max_rows = (avail > 32768) ? (long)((avail - 32768) / 1024) : 0;  // 32 KB tail-read slack
    int srows = (int)((max_rows / 64) * 64);
    if (srows > N_NODES + 63) srows = ((N_NODES + 63) / 64) * 64;
    const bool split_ok = (srows >= 128);

    // zero scratch via memset nodes (graph-capturable), then edge sort
    hipMemsetAsync(counts, 0, (size_t)NR * 4, stream);
    hipMemsetAsync(gsum, 0, (size_t)(64 * 128 + 64) * 4, stream);
    k_hist<<<(N_EDGES + 255) / 256, 256, 0, stream>>>(edge_index, edge_type, counts);
    k_scan1<<<NB1, 256, 0, stream>>>(counts, cursor, bsum);
    k_scan2<<<1, 1024, 0, stream>>>(bsum, NB1);
    k_scan3<<<(NR + 255) / 256, 256, 0, stream>>>(cursor, bsum, rowptr, cursor);
    k_scatter<<<(N_EDGES + 255) / 256, 256, 0, stream>>>(edge_index, edge_type, cursor, srcs);

    // x0 gather + merged weight prep
    k_gather<<<(N_NODES * 64 + 255) / 256, 256, 0, stream>>>(node_type, node_emb, xa);
    k_wprep_all<<<(WT_TOTAL + W8_TOTAL + 255) / 256, 256, 0, stream>>>(rel_w, root_w, WT, W8);

    const int mblocks = (N_NODES + BM - 1) / BM;   // 1563 (fallback)
    unsigned int* xcur = xa;
    unsigned int* xnext = xb;
    for (int l = 0; l < N_LAYER; ++l) {
        const unsigned short* Wl  = WT + (size_t)l * 9 * 16384;
        const unsigned short* W8l = W8 + (size_t)l * 8 * 8192;
        const float* bl = bias + (size_t)l * 128;
        if (split_ok) {
            for (int d0 = 0; d0 < N_NODES; d0 += srows) {
                int rows = N_NODES - d0;
                if (rows > srows) rows = srows;
                int ab = (rows + 15) / 16;                 // 16 nodes per block (4 waves x 4)
                int gb = (rows + BM2 - 1) / BM2;
                k_agg<<<ab, 256, 0, stream>>>(xcur, rowptr, srcs, Ag8, d0, rows, srows);
                k_gemm<<<gb, 256, 0, stream>>>(Ag8, xcur, xnext, W8l, Wl, bl, d0, srows);
            }
        } else {
            k_layer_fb<<<mblocks, 256, 0, stream>>>(xcur, xnext, rowptr, srcs, Wl, bl);
        }
        unsigned int* tmp = xcur; xcur = xnext; xnext = tmp;
    }

    // pool + heads (final activations are in xcur after swap)
    k_pool<<<(N_NODES + 255) / 256, 256, 0, stream>>>(xcur, batch, gsum, gcnt);
    k_heads<<<64, 128, 0, stream>>>(gsum, gcnt, rw1, rb1, rw2, rb2,
                                    sw1, sb1, sw2, sb2, out);
}

// Round 13
// 427.569 us; speedup vs baseline: 1.5421x; 1.0739x over previous
//
#include <hip/hip_runtime.h>
#include <hip/hip_bf16.h>

#define N_NODES 100000
#define N_EDGES 600000
#define DIM     128
#define N_REL   8
#define N_GRAPH 64
#define N_LAYER 3
#define NR      (N_NODES * N_REL)   // 800000
#define NB1     782                 // ceil(NR / 1024)

typedef __attribute__((ext_vector_type(4))) float float4v;
typedef __attribute__((ext_vector_type(2))) float float2v;
typedef unsigned long long ull;

// XOR-swizzle, 8-B granules, 128-B rows (fp8 tiles): 16 granules/row
__device__ __forceinline__ int gswz8(int row, int g) {
    return row * 16 + (g ^ (row & 15));
}

// ---------------- counting sort of edges by seg = dst*8 + rel (dst-major) ----------------
__global__ void k_hist(const int* __restrict__ ei, const int* __restrict__ et,
                       int* __restrict__ counts) {
    int e = blockIdx.x * 256 + threadIdx.x;
    if (e < N_EDGES) {
        int seg = ei[N_EDGES + e] * N_REL + et[e];
        atomicAdd(&counts[seg], 1);
    }
}

__global__ __launch_bounds__(256) void k_scan1(const int* __restrict__ cnts,
                                               int* __restrict__ part,
                                               int* __restrict__ bsum) {
    __shared__ int sh[256];
    int t = threadIdx.x;
    int base = blockIdx.x * 1024 + t * 4;
    int v0 = (base + 0 < NR) ? cnts[base + 0] : 0;
    int v1 = (base + 1 < NR) ? cnts[base + 1] : 0;
    int v2 = (base + 2 < NR) ? cnts[base + 2] : 0;
    int v3 = (base + 3 < NR) ? cnts[base + 3] : 0;
    int tot = v0 + v1 + v2 + v3;
    sh[t] = tot;
    __syncthreads();
    for (int off = 1; off < 256; off <<= 1) {
        int x = (t >= off) ? sh[t - off] : 0;
        __syncthreads();
        sh[t] += x;
        __syncthreads();
    }
    int exc = sh[t] - tot;
    if (base + 0 < NR) part[base + 0] = exc;
    if (base + 1 < NR) part[base + 1] = exc + v0;
    if (base + 2 < NR) part[base + 2] = exc + v0 + v1;
    if (base + 3 < NR) part[base + 3] = exc + v0 + v1 + v2;
    if (t == 255) bsum[blockIdx.x] = sh[t];
}

__global__ __launch_bounds__(1024) void k_scan2(int* __restrict__ bsum, int nb) {
    __shared__ int sh[1024];
    int t = threadIdx.x;
    int v = (t < nb) ? bsum[t] : 0;
    sh[t] = v;
    __syncthreads();
    for (int off = 1; off < 1024; off <<= 1) {
        int x = (t >= off) ? sh[t - off] : 0;
        __syncthreads();
        sh[t] += x;
        __syncthreads();
    }
    if (t < nb) bsum[t] = sh[t] - v;   // exclusive block offsets
}

__global__ void k_scan3(const int* __restrict__ part, const int* __restrict__ bsum,
                        int* __restrict__ rowptr, int* __restrict__ cursor) {
    int i = blockIdx.x * 256 + threadIdx.x;
    if (i < NR) {
        int v = part[i] + bsum[i >> 10];
        rowptr[i] = v;
        cursor[i] = v;
    }
    if (i == 0) rowptr[NR] = N_EDGES;
}

__global__ void k_scatter(const int* __restrict__ ei, const int* __restrict__ et,
                          int* __restrict__ cursor, int* __restrict__ srcs) {
    int e = blockIdx.x * 256 + threadIdx.x;
    if (e < N_EDGES) {
        int seg = ei[N_EDGES + e] * N_REL + et[e];
        int p = atomicAdd(&cursor[seg], 1);
        srcs[p] = ei[e];
    }
}

// ---------------- x0 = fp8(node_emb[node_type]), pi-permuted rows ----------------
// byte position p of a row holds natural col (p&7)*16 + (p>>3)
__global__ void k_gather8(const int* __restrict__ nt, const float* __restrict__ emb,
                          unsigned int* __restrict__ x8) {
    int gid = blockIdx.x * 256 + threadIdx.x;
    if (gid < N_NODES * 32) {
        int n = gid >> 5, up = gid & 31;
        const float* row = emb + (size_t)nt[n] * DIM;
        int p0 = up * 4;
        float f0 = row[((p0 + 0) & 7) * 16 + ((p0 + 0) >> 3)];
        float f1 = row[((p0 + 1) & 7) * 16 + ((p0 + 1) >> 3)];
        float f2 = row[((p0 + 2) & 7) * 16 + ((p0 + 2) >> 3)];
        float f3 = row[((p0 + 3) & 7) * 16 + ((p0 + 3) >> 3)];
        int u = __builtin_amdgcn_cvt_pk_fp8_f32(f0, f1, 0, false);
        u = __builtin_amdgcn_cvt_pk_fp8_f32(f2, f3, u, true);
        x8[gid] = (unsigned int)u;
    }
}

// ---------------- weight prep: fp8 e4m3, 9 planes/layer (8 rel + root), pi k-order ----
#define W8_TOTAL (N_LAYER * 9 * 8192)
__global__ void k_wprep9(const float* __restrict__ relw, const float* __restrict__ rootw,
                         unsigned short* __restrict__ W8) {
    int gid = blockIdx.x * 256 + threadIdx.x;
    if (gid < W8_TOTAL) {
        int l = gid / (9 * 8192);
        int rem = gid - l * 9 * 8192;
        int r = rem >> 13;                 // plane 0..8
        int idx = rem & 8191;
        int n = idx >> 6, p2 = idx & 63;
        int pos0 = 2 * p2, pos1 = 2 * p2 + 1;
        int k0 = (pos0 & 7) * 16 + (pos0 >> 3);
        int k1 = (pos1 & 7) * 16 + (pos1 >> 3);
        float w0, w1;
        if (r < 8) {
            const float* base = relw + ((size_t)(l * 8 + r) * 128) * 128 + n;
            w0 = base[(size_t)k0 * 128];
            w1 = base[(size_t)k1 * 128];
        } else {
            const float* base = rootw + (size_t)l * 128 * 128 + n;
            w0 = base[(size_t)k0 * 128];
            w1 = base[(size_t)k1 * 128];
        }
        int pk = __builtin_amdgcn_cvt_pk_fp8_f32(w0, w1, 0, false);
        W8[gid] = (unsigned short)(pk & 0xffff);
    }
}

// ---------------- per-dst aggregation: 4 nodes/wave, fp8 in, fp8 out ----------------
// Quarter q (16 lanes) owns node 4w+q; lane j covers byte positions 8j..8j+7.
__global__ __launch_bounds__(256) void k_agg(
    const unsigned int* __restrict__ x8,    // [N][32] fp8 rows (pi order)
    const int* __restrict__ rowptr,         // [NR+1], seg = dst*8 + rel
    const int* __restrict__ srcs,           // [E] sorted by seg
    unsigned int* __restrict__ Ag8,         // [8][srows][32] fp8 (pi order)
    int d0, int rows, int srows)
{
    const int t = threadIdx.x;
    const int wv = t >> 6, lane = t & 63;
    const int q = lane >> 4, j = lane & 15;
    const int nb0 = (blockIdx.x * 4 + wv) * 4;     // first local node of this wave
    if (nb0 >= rows) return;
    const int myn = nb0 + q;
    const bool nvalid = (myn < rows);

    int pr = 0;
    {
        int idx = (d0 + nb0) * 8 + lane;
        if (idx > NR) idx = NR;
        if (lane < 33) pr = rowptr[idx];
    }
    const int P0 = __shfl(pr, 0);
    const int Dtot = __shfl(pr, 32) - P0;

    int my_src = 0;
    if (lane < Dtot) my_src = srcs[P0 + lane];

    const uint2* x2p = (const uint2*)x8;           // row = 16 uint2

    for (int r = 0; r < 8; ++r) {
        int e0 = __shfl(pr, q * 8 + r);
        int e1 = __shfl(pr, q * 8 + r + 1);
        int cnt = e1 - e0;                         // quarter-uniform
        int m1 = max(cnt, __shfl_xor(cnt, 16));
        int maxc = max(m1, __shfl_xor(m1, 32));    // wave max
        float2v A0 = {0.f, 0.f}, A1 = {0.f, 0.f}, A2 = {0.f, 0.f}, A3 = {0.f, 0.f};
        int k = 0;
        for (; k + 2 <= maxc; k += 2) {
            int ei0 = e0 + k, ei1 = e0 + k + 1;
            int r0 = ei0 - P0, r1 = ei1 - P0;
            int s0 = __shfl(my_src, r0 & 63);
            int s1 = __shfl(my_src, r1 & 63);
            if (r0 >= 64) s0 = srcs[ei0];          // essentially never
            if (r1 >= 64) s1 = srcs[ei1];
            bool v0 = (k < cnt), v1 = (k + 1 < cnt);
            uint2 u0, u1;
            if (v0) u0 = x2p[(size_t)s0 * 16 + j];
            if (v1) u1 = x2p[(size_t)s1 * 16 + j];
            if (v0) {
                A0 += __builtin_amdgcn_cvt_pk_f32_fp8((int)u0.x, false);
                A1 += __builtin_amdgcn_cvt_pk_f32_fp8((int)u0.x, true);
                A2 += __builtin_amdgcn_cvt_pk_f32_fp8((int)u0.y, false);
                A3 += __builtin_amdgcn_cvt_pk_f32_fp8((int)u0.y, true);
            }
            if (v1) {
                A0 += __builtin_amdgcn_cvt_pk_f32_fp8((int)u1.x, false);
                A1 += __builtin_amdgcn_cvt_pk_f32_fp8((int)u1.x, true);
                A2 += __builtin_amdgcn_cvt_pk_f32_fp8((int)u1.y, false);
                A3 += __builtin_amdgcn_cvt_pk_f32_fp8((int)u1.y, true);
            }
        }
        if (k < maxc) {
            int ei = e0 + k;
            int ridx = ei - P0;
            int s = __shfl(my_src, ridx & 63);
            if (ridx >= 64) s = srcs[ei];
            if (k < cnt) {
                uint2 u = x2p[(size_t)s * 16 + j];
                A0 += __builtin_amdgcn_cvt_pk_f32_fp8((int)u.x, false);
                A1 += __builtin_amdgcn_cvt_pk_f32_fp8((int)u.x, true);
                A2 += __builtin_amdgcn_cvt_pk_f32_fp8((int)u.y, false);
                A3 += __builtin_amdgcn_cvt_pk_f32_fp8((int)u.y, true);
            }
        }
        float inv = (cnt > 0) ? 1.0f / (float)cnt : 0.f;
        float2v iv = {inv, inv};
        A0 *= iv; A1 *= iv; A2 *= iv; A3 *= iv;
        int u0 = __builtin_amdgcn_cvt_pk_fp8_f32(A0.x, A0.y, 0, false);
        u0 = __builtin_amdgcn_cvt_pk_fp8_f32(A1.x, A1.y, u0, true);
        int u1 = __builtin_amdgcn_cvt_pk_fp8_f32(A2.x, A2.y, 0, false);
        u1 = __builtin_amdgcn_cvt_pk_fp8_f32(A3.x, A3.y, u1, true);
        if (nvalid) {
            uint2 v; v.x = (unsigned int)u0; v.y = (unsigned int)u1;
            *(uint2*)&Ag8[((size_t)r * srows + myn) * 32 + j * 2] = v;
        }
    }
}

// ---------------- dense MFMA GEMM: 9 uniform fp8 chunks, ping-pong, fp8 out ----------------
#define BM2 128
__global__ __launch_bounds__(256) void k_gemm(
    const unsigned int* __restrict__ Ag8,   // [8][srows][32] fp8
    const unsigned int* __restrict__ x8in,  // [N][32] fp8 (chunk 8 A-plane)
    unsigned int* __restrict__ x8out,       // [N][32] fp8
    const unsigned short* __restrict__ W8,  // [9][128n][64kp] fp8 pairs (this layer)
    const float* __restrict__ bias,         // [128]
    int d0, int srows)
{
    __shared__ __align__(16) ull Als[4096];  // 2 x 16 KB ping-pong
    __shared__ __align__(16) ull Bls[4096];  // 2 x 16 KB ping-pong
    const int t = threadIdx.x;
    const int wv = t >> 6, lane = t & 63;
    const int quad = lane >> 4, l15 = lane & 15;
    const int m0 = d0 + blockIdx.x * BM2;

    float4v acc[2][8];
#pragma unroll
    for (int nt = 0; nt < 8; ++nt) {
        float bc = bias[nt * 16 + l15];
        acc[0][nt] = (float4v){bc, bc, bc, bc};
        acc[1][nt] = (float4v){bc, bc, bc, bc};
    }

    const ull* Abase = (const ull*)Ag8 + (size_t)(m0 - d0) * 16;
    const size_t cstride = (size_t)srows * 16;      // ull per chunk plane
    const ull* Aroot = (const ull*)x8in + (size_t)m0 * 16;

    // prefetch chunk 0 (A and B) into registers, write into buf 0
    ull aR[8], bR[8];
    {
        const ull* Ac = Abase;
        const ull* Wc = (const ull*)W8;
#pragma unroll
        for (int i = 0; i < 8; ++i) {
            aR[i] = Ac[t + 256 * i];
            bR[i] = Wc[t + 256 * i];
        }
    }
#pragma unroll
    for (int i = 0; i < 8; ++i) {
        int idx = t + 256 * i;
        int sw = gswz8(idx >> 4, idx & 15);
        Als[sw] = aR[i];
        Bls[sw] = bR[i];
    }
    __syncthreads();

    // ---- 9 fp8 chunks (8 rel + root), single barrier per chunk ----
    for (int c = 0; c < 9; ++c) {
        const int cur = (c & 1) * 2048;
        if (c < 8) {                               // issue next-chunk loads (hidden by MFMA)
            const ull* Ac = (c + 1 < 8) ? (Abase + (size_t)(c + 1) * cstride) : Aroot;
            const ull* Wc = (const ull*)(W8 + (size_t)(c + 1) * 8192);
#pragma unroll
            for (int i = 0; i < 8; ++i) {
                aR[i] = Ac[t + 256 * i];
                bR[i] = Wc[t + 256 * i];
            }
        }
#pragma unroll
        for (int kk = 0; kk < 4; ++kk) {
            int g = kk * 4 + quad;
            long long a0 = (long long)Als[cur + (wv * 32 + l15) * 16 + (g ^ l15)];
            long long a1 = (long long)Als[cur + (wv * 32 + 16 + l15) * 16 + (g ^ l15)];
#pragma unroll
            for (int nt = 0; nt < 8; ++nt) {
                long long b8 = (long long)Bls[cur + (nt * 16 + l15) * 16 + (g ^ l15)];
                acc[0][nt] = __builtin_amdgcn_mfma_f32_16x16x32_fp8_fp8(a0, b8, acc[0][nt], 0, 0, 0);
                acc[1][nt] = __builtin_amdgcn_mfma_f32_16x16x32_fp8_fp8(a1, b8, acc[1][nt], 0, 0, 0);
            }
        }
        if (c < 8) {                               // write prefetched data into other buf
            const int nxt = ((c + 1) & 1) * 2048;
#pragma unroll
            for (int i = 0; i < 8; ++i) {
                int idx = t + 256 * i;
                int sw = gswz8(idx >> 4, idx & 15);
                Als[nxt + sw] = aR[i];
                Bls[nxt + sw] = bR[i];
            }
            __syncthreads();
        }
    }
    // ---- epilogue: relu, fp8 pack (pi order: thread's 8 nt-bytes are contiguous) ----
    ull* outs = (ull*)x8out;
#pragma unroll
    for (int rt = 0; rt < 2; ++rt) {
#pragma unroll
        for (int i = 0; i < 4; ++i) {
            int row = m0 + wv * 32 + rt * 16 + quad * 4 + i;
            float v0 = acc[rt][0][i], v1 = acc[rt][1][i];
            float v2 = acc[rt][2][i], v3 = acc[rt][3][i];
            float v4 = acc[rt][4][i], v5 = acc[rt][5][i];
            float v6 = acc[rt][6][i], v7 = acc[rt][7][i];
            v0 = v0 > 0.f ? v0 : 0.f;  v1 = v1 > 0.f ? v1 : 0.f;
            v2 = v2 > 0.f ? v2 : 0.f;  v3 = v3 > 0.f ? v3 : 0.f;
            v4 = v4 > 0.f ? v4 : 0.f;  v5 = v5 > 0.f ? v5 : 0.f;
            v6 = v6 > 0.f ? v6 : 0.f;  v7 = v7 > 0.f ? v7 : 0.f;
            int lo = __builtin_amdgcn_cvt_pk_fp8_f32(v0, v1, 0, false);
            lo = __builtin_amdgcn_cvt_pk_fp8_f32(v2, v3, lo, true);
            int hi = __builtin_amdgcn_cvt_pk_fp8_f32(v4, v5, 0, false);
            hi = __builtin_amdgcn_cvt_pk_fp8_f32(v6, v7, hi, true);
            if (row < N_NODES) {
                ull w = ((ull)(unsigned int)hi << 32) | (unsigned int)lo;
                outs[(size_t)row * 16 + l15] = w;
            }
        }
    }
}

// ---------------- global mean pool (batch sorted): 64 nodes/wave, fp8 in ----------------
__global__ __launch_bounds__(256) void k_pool(const unsigned int* __restrict__ x8,
                                              const int* __restrict__ batch,
                                              float* __restrict__ gsum,
                                              int* __restrict__ gcnt) {
    const int wv = threadIdx.x >> 6, lane = threadIdx.x & 63;
    const int n0 = (blockIdx.x * 4 + wv) * 64;
    if (n0 >= N_NODES) return;
    int n1 = n0 + 64;
    if (n1 > N_NODES) n1 = N_NODES;
    const int nb = n1 - n0;
    const unsigned short* xs = (const unsigned short*)x8;   // row = 64 ushorts
    int bb = batch[n0 + (lane < nb ? lane : nb - 1)];
    float2v A = {0.f, 0.f};
    int run = 0;
    int cur = __shfl(bb, 0);
    for (int base = 0; base < nb; base += 8) {
        unsigned int u[8];
        int m = nb - base;
#pragma unroll
        for (int qq = 0; qq < 8; ++qq)
            if (qq < m) u[qq] = xs[(size_t)(n0 + base + qq) * 64 + lane];
#pragma unroll
        for (int qq = 0; qq < 8; ++qq) {
            if (qq < m) {
                int b = __shfl(bb, base + qq);
                if (b != cur) {
                    atomicAdd(&gsum[cur * 128 + lane * 2], A.x);
                    atomicAdd(&gsum[cur * 128 + lane * 2 + 1], A.y);
                    if (lane == 0) atomicAdd(&gcnt[cur], run);
                    A = (float2v){0.f, 0.f};
                    run = 0;
                    cur = b;
                }
                A += __builtin_amdgcn_cvt_pk_f32_fp8((int)u[qq], false);
                ++run;
            }
        }
    }
    atomicAdd(&gsum[cur * 128 + lane * 2], A.x);
    atomicAdd(&gsum[cur * 128 + lane * 2 + 1], A.y);
    if (lane == 0) atomicAdd(&gcnt[cur], run);
}

// ---------------- MLP heads (fp32; un-permutes g) ----------------
__global__ __launch_bounds__(128) void k_heads(
    const float* __restrict__ gsum, const int* __restrict__ gcnt,
    const float* __restrict__ rw1, const float* __restrict__ rb1,
    const float* __restrict__ rw2, const float* __restrict__ rb2,
    const float* __restrict__ sw1, const float* __restrict__ sb1,
    const float* __restrict__ sw2, const float* __restrict__ sb2,
    float* __restrict__ out) {
    __shared__ float g[128];
    __shared__ float parts[2];
    int b = blockIdx.x, t = threadIdx.x;
    int c = gcnt[b];
    float invc = 1.0f / (float)(c > 0 ? c : 1);
    g[((t & 7) << 4) | (t >> 3)] = gsum[b * 128 + t] * invc;   // position -> natural col
    __syncthreads();
    float acc = rb1[t];
    for (int d = 0; d < 128; ++d) acc += g[d] * rw1[d * 128 + t];
    float h = acc > 0.f ? acc : 0.f;
    float p = h * rw2[t];
    for (int o = 32; o > 0; o >>= 1) p += __shfl_down(p, o);
    if ((t & 63) == 0) parts[t >> 6] = p;
    __syncthreads();
    if (t == 0) out[b] = parts[0] + parts[1] + rb2[0];
    __syncthreads();
    acc = sb1[t];
    for (int d = 0; d < 128; ++d) acc += g[d] * sw1[d * 128 + t];
    h = acc > 0.f ? acc : 0.f;
    p = h * sw2[t];
    for (int o = 32; o > 0; o >>= 1) p += __shfl_down(p, o);
    if ((t & 63) == 0) parts[t >> 6] = p;
    __syncthreads();
    if (t == 0) out[64 + b] = parts[0] + parts[1] + sb2[0];
}

extern "C" void kernel_launch(void* const* d_in, const int* in_sizes, int n_in,
                              void* d_out, int out_size, void* d_ws, size_t ws_size,
                              hipStream_t stream) {
    const int*   node_type  = (const int*)d_in[0];
    const int*   edge_index = (const int*)d_in[1];
    const int*   edge_type  = (const int*)d_in[2];
    const int*   batch      = (const int*)d_in[3];
    const float* node_emb   = (const float*)d_in[4];
    const float* rel_w      = (const float*)d_in[5];
    const float* root_w     = (const float*)d_in[6];
    const float* bias       = (const float*)d_in[7];
    const float* rw1        = (const float*)d_in[8];
    const float* rb1        = (const float*)d_in[9];
    const float* rw2        = (const float*)d_in[10];
    const float* rb2        = (const float*)d_in[11];
    const float* sw1        = (const float*)d_in[12];
    const float* sb1        = (const float*)d_in[13];
    const float* sw2        = (const float*)d_in[14];
    const float* sb2        = (const float*)d_in[15];
    float* out = (float*)d_out;

    char* ws = (char*)d_ws;
    size_t off = 0;
    auto alloc = [&](size_t bytes) -> void* {
        void* p = ws + off;
        off += (bytes + 255) & ~(size_t)255;
        return p;
    };
    // ---- persistent region ----
    unsigned int*   x8a    = (unsigned int*)alloc((size_t)N_NODES * 32 * 4);  // 12.8 MB
    unsigned int*   x8b    = (unsigned int*)alloc((size_t)N_NODES * 32 * 4);
    int*            rowptr = (int*)alloc((size_t)(NR + 1) * 4);
    int*            srcs   = (int*)alloc((size_t)N_EDGES * 4);
    int*            bsum   = (int*)alloc(1024 * 4);
    unsigned short* W8     = (unsigned short*)alloc((size_t)W8_TOTAL * 2);
    float*          gsum   = (float*)alloc((64 * 128 + 64) * 4);
    int*            gcnt   = (int*)(gsum + 64 * 128);
    size_t off_common = off;
    // ---- scratch region: sort temps, later overlapped by Ag8 slices ----
    int*            cursor = (int*)alloc((size_t)NR * 4);
    int*            counts = (int*)alloc((size_t)NR * 4);
    size_t off_sort = off;
    if (off_sort > ws_size) return;                // cannot run at all
    unsigned int*   Ag8    = (unsigned int*)(ws + off_common);  // overlaps cursor/counts
    size_t avail = ws_size - off_common;
    long max_rows = (avail > 32768) ? (long)((avail - 32768) / 1024) : 0;  // 32 KB tail slack
    int srows = (int)((max_rows / 64) * 64);
    if (srows > N_NODES + 63) srows = ((N_NODES + 63) / 64) * 64;
    if (srows < 128) return;                       // insufficient workspace — fail visibly

    // zero scratch via memset nodes (graph-capturable), then edge sort
    hipMemsetAsync(counts, 0, (size_t)NR * 4, stream);
    hipMemsetAsync(gsum, 0, (size_t)(64 * 128 + 64) * 4, stream);
    k_hist<<<(N_EDGES + 255) / 256, 256, 0, stream>>>(edge_index, edge_type, counts);
    k_scan1<<<NB1, 256, 0, stream>>>(counts, cursor, bsum);
    k_scan2<<<1, 1024, 0, stream>>>(bsum, NB1);
    k_scan3<<<(NR + 255) / 256, 256, 0, stream>>>(cursor, bsum, rowptr, cursor);
    k_scatter<<<(N_EDGES + 255) / 256, 256, 0, stream>>>(edge_index, edge_type, cursor, srcs);

    // x0 gather (fp8, pi order) + weight prep (9 fp8 planes/layer)
    k_gather8<<<(N_NODES * 32 + 255) / 256, 256, 0, stream>>>(node_type, node_emb, x8a);
    k_wprep9<<<(W8_TOTAL + 255) / 256, 256, 0, stream>>>(rel_w, root_w, W8);

    unsigned int* xcur = x8a;
    unsigned int* xnext = x8b;
    for (int l = 0; l < N_LAYER; ++l) {
        const unsigned short* W8l = W8 + (size_t)l * 9 * 8192;
        const float* bl = bias + (size_t)l * 128;
        for (int d0 = 0; d0 < N_NODES; d0 += srows) {
            int rows = N_NODES - d0;
            if (rows > srows) rows = srows;
            int ab = (rows + 15) / 16;                 // 16 nodes per block (4 waves x 4)
            int gb = (rows + BM2 - 1) / BM2;
            k_agg<<<ab, 256, 0, stream>>>(xcur, rowptr, srcs, Ag8, d0, rows, srows);
            k_gemm<<<gb, 256, 0, stream>>>(Ag8, xcur, xnext, W8l, bl, d0, srows);
        }
        unsigned int* tmp = xcur; xcur = xnext; xnext = tmp;
    }

    // pool + heads (final activations are in xcur after swap)
    k_pool<<<(N_NODES + 255) / 256, 256, 0, stream>>>(xcur, batch, gsum, gcnt);
    k_heads<<<64, 128, 0, stream>>>(gsum, gcnt, rw1, rb1, rw2, rb2,
                                    sw1, sb1, sw2, sb2, out);
}

// Round 15
// 421.925 us; speedup vs baseline: 1.5627x; 1.0134x over previous
//
#include <hip/hip_runtime.h>
#include <hip/hip_bf16.h>

#define N_NODES 100000
#define N_EDGES 600000
#define DIM     128
#define N_REL   8
#define N_GRAPH 64
#define N_LAYER 3
#define NR      (N_NODES * N_REL)   // 800000
#define NB1     782                 // ceil(NR / 1024)

typedef __attribute__((ext_vector_type(4))) float float4v;
typedef __attribute__((ext_vector_type(2))) float float2v;
typedef unsigned long long ull;

// XOR-swizzle, 8-B granules, 128-B rows (B fp8 tiles): 16 granules/row
__device__ __forceinline__ int gswz8(int row, int g) {
    return row * 16 + (g ^ (row & 15));
}

// ---------------- counting sort of edges by seg = dst*8 + rel (dst-major) ----------------
__global__ void k_hist(const int* __restrict__ ei, const int* __restrict__ et,
                       int* __restrict__ counts) {
    int e = blockIdx.x * 256 + threadIdx.x;
    if (e < N_EDGES) {
        int seg = ei[N_EDGES + e] * N_REL + et[e];
        atomicAdd(&counts[seg], 1);
    }
}

__global__ __launch_bounds__(256) void k_scan1(const int* __restrict__ cnts,
                                               int* __restrict__ part,
                                               int* __restrict__ bsum) {
    __shared__ int sh[256];
    int t = threadIdx.x;
    int base = blockIdx.x * 1024 + t * 4;
    int v0 = (base + 0 < NR) ? cnts[base + 0] : 0;
    int v1 = (base + 1 < NR) ? cnts[base + 1] : 0;
    int v2 = (base + 2 < NR) ? cnts[base + 2] : 0;
    int v3 = (base + 3 < NR) ? cnts[base + 3] : 0;
    int tot = v0 + v1 + v2 + v3;
    sh[t] = tot;
    __syncthreads();
    for (int off = 1; off < 256; off <<= 1) {
        int x = (t >= off) ? sh[t - off] : 0;
        __syncthreads();
        sh[t] += x;
        __syncthreads();
    }
    int exc = sh[t] - tot;
    if (base + 0 < NR) part[base + 0] = exc;
    if (base + 1 < NR) part[base + 1] = exc + v0;
    if (base + 2 < NR) part[base + 2] = exc + v0 + v1;
    if (base + 3 < NR) part[base + 3] = exc + v0 + v1 + v2;
    if (t == 255) bsum[blockIdx.x] = sh[t];
}

__global__ __launch_bounds__(1024) void k_scan2(int* __restrict__ bsum, int nb) {
    __shared__ int sh[1024];
    int t = threadIdx.x;
    int v = (t < nb) ? bsum[t] : 0;
    sh[t] = v;
    __syncthreads();
    for (int off = 1; off < 1024; off <<= 1) {
        int x = (t >= off) ? sh[t - off] : 0;
        __syncthreads();
        sh[t] += x;
        __syncthreads();
    }
    if (t < nb) bsum[t] = sh[t] - v;   // exclusive block offsets
}

__global__ void k_scan3(const int* __restrict__ part, const int* __restrict__ bsum,
                        int* __restrict__ rowptr, int* __restrict__ cursor) {
    int i = blockIdx.x * 256 + threadIdx.x;
    if (i < NR) {
        int v = part[i] + bsum[i >> 10];
        rowptr[i] = v;
        cursor[i] = v;
    }
    if (i == 0) rowptr[NR] = N_EDGES;
}

__global__ void k_scatter(const int* __restrict__ ei, const int* __restrict__ et,
                          int* __restrict__ cursor, int* __restrict__ srcs) {
    int e = blockIdx.x * 256 + threadIdx.x;
    if (e < N_EDGES) {
        int seg = ei[N_EDGES + e] * N_REL + et[e];
        int p = atomicAdd(&cursor[seg], 1);
        srcs[p] = ei[e];
    }
}

// ---------------- x0 = fp8(node_emb[node_type]), pi-permuted rows ----------------
// byte position p of a row holds natural col (p&7)*16 + (p>>3)
__global__ void k_gather8(const int* __restrict__ nt, const float* __restrict__ emb,
                          unsigned int* __restrict__ x8) {
    int gid = blockIdx.x * 256 + threadIdx.x;
    if (gid < N_NODES * 32) {
        int n = gid >> 5, up = gid & 31;
        const float* row = emb + (size_t)nt[n] * DIM;
        int p0 = up * 4;
        float f0 = row[((p0 + 0) & 7) * 16 + ((p0 + 0) >> 3)];
        float f1 = row[((p0 + 1) & 7) * 16 + ((p0 + 1) >> 3)];
        float f2 = row[((p0 + 2) & 7) * 16 + ((p0 + 2) >> 3)];
        float f3 = row[((p0 + 3) & 7) * 16 + ((p0 + 3) >> 3)];
        int u = __builtin_amdgcn_cvt_pk_fp8_f32(f0, f1, 0, false);
        u = __builtin_amdgcn_cvt_pk_fp8_f32(f2, f3, u, true);
        x8[gid] = (unsigned int)u;
    }
}

// ---------------- weight prep: fp8 e4m3, 9 planes/layer (8 rel + root), pi k-order ----
#define W8_TOTAL (N_LAYER * 9 * 8192)
__global__ void k_wprep9(const float* __restrict__ relw, const float* __restrict__ rootw,
                         unsigned short* __restrict__ W8) {
    int gid = blockIdx.x * 256 + threadIdx.x;
    if (gid < W8_TOTAL) {
        int l = gid / (9 * 8192);
        int rem = gid - l * 9 * 8192;
        int r = rem >> 13;                 // plane 0..8
        int idx = rem & 8191;
        int n = idx >> 6, p2 = idx & 63;
        int pos0 = 2 * p2, pos1 = 2 * p2 + 1;
        int k0 = (pos0 & 7) * 16 + (pos0 >> 3);
        int k1 = (pos1 & 7) * 16 + (pos1 >> 3);
        float w0, w1;
        if (r < 8) {
            const float* base = relw + ((size_t)(l * 8 + r) * 128) * 128 + n;
            w0 = base[(size_t)k0 * 128];
            w1 = base[(size_t)k1 * 128];
        } else {
            const float* base = rootw + (size_t)l * 128 * 128 + n;
            w0 = base[(size_t)k0 * 128];
            w1 = base[(size_t)k1 * 128];
        }
        int pk = __builtin_amdgcn_cvt_pk_fp8_f32(w0, w1, 0, false);
        W8[gid] = (unsigned short)(pk & 0xffff);
    }
}

// ---------------- per-dst aggregation: 4 nodes/wave, fp8 in, FRAGMENT-ORDER fp8 out ----
// Quarter q (16 lanes) owns node 4w+q; lane j covers byte positions 8j..8j+7.
// Wave-uniform maxc loop: every __shfl executes with all 64 lanes active (bpermute
// returns 0 from EXEC-inactive source lanes — divergent-loop shfl is UB; see r14).
__global__ __launch_bounds__(256) void k_agg(
    const unsigned int* __restrict__ x8,    // [N][32] fp8 rows (pi order)
    const int* __restrict__ rowptr,         // [NR+1], seg = dst*8 + rel
    const int* __restrict__ srcs,           // [E] sorted by seg
    unsigned int* __restrict__ Ag8,         // [8] fragment-order planes
    int d0, int rows, int srows)
{
    const int t = threadIdx.x;
    const int wv = t >> 6, lane = t & 63;
    const int q = lane >> 4, j = lane & 15;
    const int nb0 = (blockIdx.x * 4 + wv) * 4;     // first local node of this wave
    if (nb0 >= rows) return;
    const int myn = nb0 + q;
    const bool nvalid = (myn < rows);

    int pr = 0;
    {
        int idx = (d0 + nb0) * 8 + lane;
        if (idx > NR) idx = NR;
        if (lane < 33) pr = rowptr[idx];
    }
    const int P0 = __shfl(pr, 0);
    const int Dtot = __shfl(pr, 32) - P0;

    int my_src = 0;
    if (lane < Dtot) my_src = srcs[P0 + lane];

    const uint2* x2p = (const uint2*)x8;           // row = 16 uint2
    uint2* Agf = (uint2*)Ag8;

    for (int r = 0; r < 8; ++r) {
        int e0 = __shfl(pr, q * 8 + r);
        int e1 = __shfl(pr, q * 8 + r + 1);
        int cnt = e1 - e0;                         // quarter-uniform
        int m1 = max(cnt, __shfl_xor(cnt, 16));
        int maxc = max(m1, __shfl_xor(m1, 32));    // wave max
        float2v A0 = {0.f, 0.f}, A1 = {0.f, 0.f}, A2 = {0.f, 0.f}, A3 = {0.f, 0.f};
        int k = 0;
        for (; k + 2 <= maxc; k += 2) {            // wave-uniform loop
            int ei0 = e0 + k, ei1 = e0 + k + 1;
            int r0 = ei0 - P0, r1 = ei1 - P0;
            int s0 = __shfl(my_src, r0 & 63);
            int s1 = __shfl(my_src, r1 & 63);
            if (r0 >= 64) s0 = srcs[ei0];          // essentially never
            if (r1 >= 64) s1 = srcs[ei1];
            bool v0 = (k < cnt), v1 = (k + 1 < cnt);
            uint2 u0, u1;
            if (v0) u0 = x2p[(size_t)s0 * 16 + j];
            if (v1) u1 = x2p[(size_t)s1 * 16 + j];
            if (v0) {
                A0 += __builtin_amdgcn_cvt_pk_f32_fp8((int)u0.x, false);
                A1 += __builtin_amdgcn_cvt_pk_f32_fp8((int)u0.x, true);
                A2 += __builtin_amdgcn_cvt_pk_f32_fp8((int)u0.y, false);
                A3 += __builtin_amdgcn_cvt_pk_f32_fp8((int)u0.y, true);
            }
            if (v1) {
                A0 += __builtin_amdgcn_cvt_pk_f32_fp8((int)u1.x, false);
                A1 += __builtin_amdgcn_cvt_pk_f32_fp8((int)u1.x, true);
                A2 += __builtin_amdgcn_cvt_pk_f32_fp8((int)u1.y, false);
                A3 += __builtin_amdgcn_cvt_pk_f32_fp8((int)u1.y, true);
            }
        }
        if (k < maxc) {
            int ei = e0 + k;
            int ridx = ei - P0;
            int s = __shfl(my_src, ridx & 63);
            if (ridx >= 64) s = srcs[ei];
            if (k < cnt) {
                uint2 u = x2p[(size_t)s * 16 + j];
                A0 += __builtin_amdgcn_cvt_pk_f32_fp8((int)u.x, false);
                A1 += __builtin_amdgcn_cvt_pk_f32_fp8((int)u.x, true);
                A2 += __builtin_amdgcn_cvt_pk_f32_fp8((int)u.y, false);
                A3 += __builtin_amdgcn_cvt_pk_f32_fp8((int)u.y, true);
            }
        }
        float inv = (cnt > 0) ? 1.0f / (float)cnt : 0.f;
        float2v iv = {inv, inv};
        A0 *= iv; A1 *= iv; A2 *= iv; A3 *= iv;
        int u0 = __builtin_amdgcn_cvt_pk_fp8_f32(A0.x, A0.y, 0, false);
        u0 = __builtin_amdgcn_cvt_pk_fp8_f32(A1.x, A1.y, u0, true);
        int u1 = __builtin_amdgcn_cvt_pk_fp8_f32(A2.x, A2.y, 0, false);
        u1 = __builtin_amdgcn_cvt_pk_fp8_f32(A3.x, A3.y, u1, true);
        if (nvalid) {
            uint2 v; v.x = (unsigned int)u0; v.y = (unsigned int)u1;
            // fragment order: plane r, group myn>>4, unit j, row myn&15
            Agf[(size_t)r * srows * 16 + (size_t)(myn >> 4) * 256 + j * 16 + (myn & 15)] = v;
        }
    }
}

// ---------------- dense MFMA GEMM: A from global fragments (no A LDS), B ping-pong ----
#define BM2 128
__global__ __launch_bounds__(256) void k_gemm(
    const unsigned int* __restrict__ Ag8,   // [8] fragment-order planes
    const unsigned int* __restrict__ x8in,  // [N][32] fp8 rows (chunk 8 A)
    unsigned int* __restrict__ x8out,       // [N][32] fp8 rows
    const unsigned short* __restrict__ W8,  // [9][128n][64kp] fp8 pairs (this layer)
    const float* __restrict__ bias,         // [128]
    int d0, int srows)
{
    __shared__ __align__(16) ull Bls[4096];  // 2 x 16 KB ping-pong (B only)
    const int t = threadIdx.x;
    const int wv = t >> 6, lane = t & 63;
    const int quad = lane >> 4, l15 = lane & 15;
    const int m0 = d0 + blockIdx.x * BM2;

    float4v acc[2][8];
#pragma unroll
    for (int nt = 0; nt < 8; ++nt) {
        float bc = bias[nt * 16 + l15];
        acc[0][nt] = (float4v){bc, bc, bc, bc};
        acc[1][nt] = (float4v){bc, bc, bc, bc};
    }

    const size_t pstride = (size_t)srows * 16;      // ull per fragment plane
    // this wave's group base (groups 2wv, 2wv+1 of this 128-row block)
    const ull* Ag = (const ull*)Ag8 + ((size_t)((m0 - d0) >> 4) + 2 * wv) * 256;
    const ull* Xr = (const ull*)x8in;

    ull aC[8], aN[8], bR[8];
    // prefetch chunk 0: A fragments (coalesced) + B rows
    {
        const ull* Wc = (const ull*)W8;
#pragma unroll
        for (int i = 0; i < 8; ++i) {
            aC[i] = Ag[(size_t)(i >> 2) * 256 + (i & 3) * 64 + lane];  // i = rt*4+kk
            bR[i] = Wc[t + 256 * i];
        }
    }
#pragma unroll
    for (int i = 0; i < 8; ++i) {
        int idx = t + 256 * i;
        Bls[gswz8(idx >> 4, idx & 15)] = bR[i];
    }
    __syncthreads();

    for (int c = 0; c < 9; ++c) {
        const int cur = (c & 1) * 2048;
        if (c < 8) {                               // prefetch next chunk under MFMA
            if (c + 1 < 8) {
                const ull* Ac = Ag + (size_t)(c + 1) * pstride;
#pragma unroll
                for (int i = 0; i < 8; ++i)
                    aN[i] = Ac[(size_t)(i >> 2) * 256 + (i & 3) * 64 + lane];
            } else {                               // root A from x8 rows (pi order)
#pragma unroll
                for (int i = 0; i < 8; ++i) {
                    int rt = i >> 2, kk = i & 3;
                    aN[i] = Xr[(size_t)(m0 + wv * 32 + rt * 16 + l15) * 16 + kk * 4 + quad];
                }
            }
            const ull* Wc = (const ull*)(W8 + (size_t)(c + 1) * 8192);
#pragma unroll
            for (int i = 0; i < 8; ++i) bR[i] = Wc[t + 256 * i];
        }
#pragma unroll
        for (int kk = 0; kk < 4; ++kk) {
            long long a0 = (long long)aC[kk];
            long long a1 = (long long)aC[4 + kk];
            int g = kk * 4 + quad;
#pragma unroll
            for (int nt = 0; nt < 8; ++nt) {
                long long b8 = (long long)Bls[cur + (nt * 16 + l15) * 16 + (g ^ l15)];
                acc[0][nt] = __builtin_amdgcn_mfma_f32_16x16x32_fp8_fp8(a0, b8, acc[0][nt], 0, 0, 0);
                acc[1][nt] = __builtin_amdgcn_mfma_f32_16x16x32_fp8_fp8(a1, b8, acc[1][nt], 0, 0, 0);
            }
        }
        if (c < 8) {
            const int nxt = ((c + 1) & 1) * 2048;
#pragma unroll
            for (int i = 0; i < 8; ++i) {
                int idx = t + 256 * i;
                Bls[nxt + gswz8(idx >> 4, idx & 15)] = bR[i];
                aC[i] = aN[i];
            }
            __syncthreads();
        }
    }
    // ---- epilogue: relu, fp8 pack (pi order rows) ----
    ull* outs = (ull*)x8out;
#pragma unroll
    for (int rt = 0; rt < 2; ++rt) {
#pragma unroll
        for (int i = 0; i < 4; ++i) {
            int row = m0 + wv * 32 + rt * 16 + quad * 4 + i;
            float v0 = acc[rt][0][i], v1 = acc[rt][1][i];
            float v2 = acc[rt][2][i], v3 = acc[rt][3][i];
            float v4 = acc[rt][4][i], v5 = acc[rt][5][i];
            float v6 = acc[rt][6][i], v7 = acc[rt][7][i];
            v0 = v0 > 0.f ? v0 : 0.f;  v1 = v1 > 0.f ? v1 : 0.f;
            v2 = v2 > 0.f ? v2 : 0.f;  v3 = v3 > 0.f ? v3 : 0.f;
            v4 = v4 > 0.f ? v4 : 0.f;  v5 = v5 > 0.f ? v5 : 0.f;
            v6 = v6 > 0.f ? v6 : 0.f;  v7 = v7 > 0.f ? v7 : 0.f;
            int lo = __builtin_amdgcn_cvt_pk_fp8_f32(v0, v1, 0, false);
            lo = __builtin_amdgcn_cvt_pk_fp8_f32(v2, v3, lo, true);
            int hi = __builtin_amdgcn_cvt_pk_fp8_f32(v4, v5, 0, false);
            hi = __builtin_amdgcn_cvt_pk_fp8_f32(v6, v7, hi, true);
            if (row < N_NODES) {
                ull w = ((ull)(unsigned int)hi << 32) | (unsigned int)lo;
                outs[(size_t)row * 16 + l15] = w;
            }
        }
    }
}

// ---------------- global mean pool (batch sorted): 64 nodes/wave, fp8 in ----------------
__global__ __launch_bounds__(256) void k_pool(const unsigned int* __restrict__ x8,
                                              const int* __restrict__ batch,
                                              float* __restrict__ gsum,
                                              int* __restrict__ gcnt) {
    const int wv = threadIdx.x >> 6, lane = threadIdx.x & 63;
    const int n0 = (blockIdx.x * 4 + wv) * 64;
    if (n0 >= N_NODES) return;
    int n1 = n0 + 64;
    if (n1 > N_NODES) n1 = N_NODES;
    const int nb = n1 - n0;
    const unsigned short* xs = (const unsigned short*)x8;   // row = 64 ushorts
    int bb = batch[n0 + (lane < nb ? lane : nb - 1)];
    float2v A = {0.f, 0.f};
    int run = 0;
    int cur = __shfl(bb, 0);
    for (int base = 0; base < nb; base += 8) {
        unsigned int u[8];
        int m = nb - base;
#pragma unroll
        for (int qq = 0; qq < 8; ++qq)
            if (qq < m) u[qq] = xs[(size_t)(n0 + base + qq) * 64 + lane];
#pragma unroll
        for (int qq = 0; qq < 8; ++qq) {
            if (qq < m) {
                int b = __shfl(bb, base + qq);
                if (b != cur) {
                    atomicAdd(&gsum[cur * 128 + lane * 2], A.x);
                    atomicAdd(&gsum[cur * 128 + lane * 2 + 1], A.y);
                    if (lane == 0) atomicAdd(&gcnt[cur], run);
                    A = (float2v){0.f, 0.f};
                    run = 0;
                    cur = b;
                }
                A += __builtin_amdgcn_cvt_pk_f32_fp8((int)u[qq], false);
                ++run;
            }
        }
    }
    atomicAdd(&gsum[cur * 128 + lane * 2], A.x);
    atomicAdd(&gsum[cur * 128 + lane * 2 + 1], A.y);
    if (lane == 0) atomicAdd(&gcnt[cur], run);
}

// ---------------- MLP heads (fp32; un-permutes g) ----------------
__global__ __launch_bounds__(128) void k_heads(
    const float* __restrict__ gsum, const int* __restrict__ gcnt,
    const float* __restrict__ rw1, const float* __restrict__ rb1,
    const float* __restrict__ rw2, const float* __restrict__ rb2,
    const float* __restrict__ sw1, const float* __restrict__ sb1,
    const float* __restrict__ sw2, const float* __restrict__ sb2,
    float* __restrict__ out) {
    __shared__ float g[128];
    __shared__ float parts[2];
    int b = blockIdx.x, t = threadIdx.x;
    int c = gcnt[b];
    float invc = 1.0f / (float)(c > 0 ? c : 1);
    g[((t & 7) << 4) | (t >> 3)] = gsum[b * 128 + t] * invc;   // position -> natural col
    __syncthreads();
    float acc = rb1[t];
    for (int d = 0; d < 128; ++d) acc += g[d] * rw1[d * 128 + t];
    float h = acc > 0.f ? acc : 0.f;
    float p = h * rw2[t];
    for (int o = 32; o > 0; o >>= 1) p += __shfl_down(p, o);
    if ((t & 63) == 0) parts[t >> 6] = p;
    __syncthreads();
    if (t == 0) out[b] = parts[0] + parts[1] + rb2[0];
    __syncthreads();
    acc = sb1[t];
    for (int d = 0; d < 128; ++d) acc += g[d] * sw1[d * 128 + t];
    h = acc > 0.f ? acc : 0.f;
    p = h * sw2[t];
    for (int o = 32; o > 0; o >>= 1) p += __shfl_down(p, o);
    if ((t & 63) == 0) parts[t >> 6] = p;
    __syncthreads();
    if (t == 0) out[64 + b] = parts[0] + parts[1] + sb2[0];
}

extern "C" void kernel_launch(void* const* d_in, const int* in_sizes, int n_in,
                              void* d_out, int out_size, void* d_ws, size_t ws_size,
                              hipStream_t stream) {
    const int*   node_type  = (const int*)d_in[0];
    const int*   edge_index = (const int*)d_in[1];
    const int*   edge_type  = (const int*)d_in[2];
    const int*   batch      = (const int*)d_in[3];
    const float* node_emb   = (const float*)d_in[4];
    const float* rel_w      = (const float*)d_in[5];
    const float* root_w     = (const float*)d_in[6];
    const float* bias       = (const float*)d_in[7];
    const float* rw1        = (const float*)d_in[8];
    const float* rb1        = (const float*)d_in[9];
    const float* rw2        = (const float*)d_in[10];
    const float* rb2        = (const float*)d_in[11];
    const float* sw1        = (const float*)d_in[12];
    const float* sb1        = (const float*)d_in[13];
    const float* sw2        = (const float*)d_in[14];
    const float* sb2        = (const float*)d_in[15];
    float* out = (float*)d_out;

    char* ws = (char*)d_ws;
    size_t off = 0;
    auto alloc = [&](size_t bytes) -> void* {
        void* p = ws + off;
        off += (bytes + 255) & ~(size_t)255;
        return p;
    };
    // ---- persistent region ----
    unsigned int*   x8a    = (unsigned int*)alloc((size_t)N_NODES * 32 * 4);  // 12.8 MB
    unsigned int*   x8b    = (unsigned int*)alloc((size_t)N_NODES * 32 * 4);
    int*            rowptr = (int*)alloc((size_t)(NR + 1) * 4);
    int*            srcs   = (int*)alloc((size_t)N_EDGES * 4);
    int*            bsum   = (int*)alloc(1024 * 4);
    unsigned short* W8     = (unsigned short*)alloc((size_t)W8_TOTAL * 2);
    float*          gsum   = (float*)alloc((64 * 128 + 64) * 4);
    int*            gcnt   = (int*)(gsum + 64 * 128);
    size_t off_common = off;
    // ---- scratch region: sort temps, later overlapped by Ag8 slices ----
    int*            cursor = (int*)alloc((size_t)NR * 4);
    int*            counts = (int*)alloc((size_t)NR * 4);
    size_t off_sort = off;
    if (off_sort > ws_size) return;                // cannot run at all
    unsigned int*   Ag8    = (unsigned int*)(ws + off_common);  // overlaps cursor/counts
    size_t avail = ws_size - off_common;
    long max_rows = (avail > 32768) ? (long)((avail - 32768) / 1024) : 0;  // 32 KB tail slack
    int srows = (int)((max_rows / 64) * 64);
    if (srows > N_NODES + 63) srows = ((N_NODES + 63) / 64) * 64;
    if (srows < 128) return;                       // insufficient workspace — fail visibly

    // zero scratch via memset nodes (graph-capturable), then edge sort
    hipMemsetAsync(counts, 0, (size_t)NR * 4, stream);
    hipMemsetAsync(gsum, 0, (size_t)(64 * 128 + 64) * 4, stream);
    k_hist<<<(N_EDGES + 255) / 256, 256, 0, stream>>>(edge_index, edge_type, counts);
    k_scan1<<<NB1, 256, 0, stream>>>(counts, cursor, bsum);
    k_scan2<<<1, 1024, 0, stream>>>(bsum, NB1);
    k_scan3<<<(NR + 255) / 256, 256, 0, stream>>>(cursor, bsum, rowptr, cursor);
    k_scatter<<<(N_EDGES + 255) / 256, 256, 0, stream>>>(edge_index, edge_type, cursor, srcs);

    // x0 gather (fp8, pi order) + weight prep (9 fp8 planes/layer)
    k_gather8<<<(N_NODES * 32 + 255) / 256, 256, 0, stream>>>(node_type, node_emb, x8a);
    k_wprep9<<<(W8_TOTAL + 255) / 256, 256, 0, stream>>>(rel_w, root_w, W8);

    unsigned int* xcur = x8a;
    unsigned int* xnext = x8b;
    for (int l = 0; l < N_LAYER; ++l) {
        const unsigned short* W8l = W8 + (size_t)l * 9 * 8192;
        const float* bl = bias + (size_t)l * 128;
        for (int d0 = 0; d0 < N_NODES; d0 += srows) {
            int rows = N_NODES - d0;
            if (rows > srows) rows = srows;
            int ab = (rows + 15) / 16;                 // 16 nodes per block (4 waves x 4)
            int gb = (rows + BM2 - 1) / BM2;
            k_agg<<<ab, 256, 0, stream>>>(xcur, rowptr, srcs, Ag8, d0, rows, srows);
            k_gemm<<<gb, 256, 0, stream>>>(Ag8, xcur, xnext, W8l, bl, d0, srows);
        }
        unsigned int* tmp = xcur; xcur = xnext; xnext = tmp;
    }

    // pool + heads (final activations are in xcur after swap)
    k_pool<<<(N_NODES + 255) / 256, 256, 0, stream>>>(xcur, batch, gsum, gcnt);
    k_heads<<<64, 128, 0, stream>>>(gsum, gcnt, rw1, rb1, rw2, rb2,
                                    sw1, sb1, sw2, sb2, out);
}